// Round 5
// baseline (315.180 us; speedup 1.0000x reference)
//
#include <hip/hip_runtime.h>
#include <math.h>

#define LOG2PI_F  0.9189385332046727f
#define INV_LN2_F 1.4426950408889634f
#define LN2_F     0.6931471805599453f
#define SSTR      66          // stack slot row stride (floats); 66: C-writes 2-way (free), 9 blocks/CU

typedef short bf16x8 __attribute__((ext_vector_type(8)));
typedef float f32x4  __attribute__((ext_vector_type(4)));

struct __align__(16) Op { int w; int c0; int c1; int leaf; };

// ---- workspace byte offsets -------------------------------------------------
#define WS_WBJ   0u          // bf16[255*4096] softmaxed weights, j-major
#define WS_A     2097152u    // float[256*64]  leaf coeff A (log2 domain)
#define WS_B     2162688u    // float[256*64]  leaf coeff B
#define WS_C     2228224u    // float[256*64]  leaf coeff C
#define WS_XT    2293760u    // float[256*2048] x gathered+transposed: xT[d][b]
#define WS_SCHED 4390912u    // Op[17*15]: 16 producer trees (L1-4) + 1 tail tree (L5-8)
#define WS_CTR   4395008u    // int[128] per-tile completion counters
#define WS_L4    4395520u    // float[16*2048*64] level-4 values (log2)  -> ends 12.78 MB

__device__ __forceinline__ short bfr(float f) {   // f32 -> bf16 RNE
    unsigned int u = __float_as_uint(f);
    u += 0x7fffu + ((u >> 16) & 1u);
    return (short)(u >> 16);
}

struct F8 { float v[8]; };
__device__ __forceinline__ F8 ld8(const float* p) {
    F8 r;
    float4 a = *(const float4*)p;
    float4 b = *(const float4*)(p + 4);
    r.v[0]=a.x; r.v[1]=a.y; r.v[2]=a.z; r.v[3]=a.w;
    r.v[4]=b.x; r.v[5]=b.y; r.v[6]=b.z; r.v[7]=b.w;
    return r;
}

// ---------------------------------------------------------------------------
// Prep: [0,255) softmax->bf16 j-major; [255,319) leaf quadratic coeffs;
// [319,575) x transpose/gather; 575: schedules + zero tile counters.
// ---------------------------------------------------------------------------
__global__ __launch_bounds__(256) void prep_kernel(
    const float* __restrict__ w1, const float* __restrict__ w2,
    const float* __restrict__ w3, const float* __restrict__ w4,
    const float* __restrict__ w5, const float* __restrict__ w6,
    const float* __restrict__ w7, const float* __restrict__ w8,
    const float* __restrict__ mu, const float* __restrict__ ls,
    const float* __restrict__ x,  const int* __restrict__ scope,
    const int* __restrict__ f1, const int* __restrict__ f2,
    const int* __restrict__ f3, const int* __restrict__ f4,
    const int* __restrict__ f5, const int* __restrict__ f6,
    const int* __restrict__ f7, const int* __restrict__ f8,
    char* __restrict__ ws)
{
    const int bx = blockIdx.x, t = threadIdx.x;
    if (bx < 255) {
        __shared__ float smax[64], ssum[64];
        const int g = bx;
        const float* src;
        if (g < 128)      src = w1 + g * 4096;
        else if (g < 192) src = w2 + (g - 128) * 4096;
        else if (g < 224) src = w3 + (g - 192) * 4096;
        else if (g < 240) src = w4 + (g - 224) * 4096;
        else if (g < 248) src = w5 + (g - 240) * 4096;
        else if (g < 252) src = w6 + (g - 248) * 4096;
        else              src = (g < 254) ? (w7 + (g - 252) * 4096) : w8;
        const int lane = t & 63, wv = t >> 6;
        for (int r = 0; r < 16; ++r) {
            int j = wv * 16 + r;
            float v = src[j * 64 + lane];
            float mx = v;
            for (int d = 1; d < 64; d <<= 1) mx = fmaxf(mx, __shfl_xor(mx, d, 64));
            float e = __expf(v - mx);
            float sm = e;
            for (int d = 1; d < 64; d <<= 1) sm += __shfl_xor(sm, d, 64);
            if (lane == 0) { smax[j] = mx; ssum[j] = sm; }
        }
        __syncthreads();
        unsigned short* dst = (unsigned short*)(ws + WS_WBJ) + g * 4096;
        for (int u = 0; u < 16; ++u) {
            int idx = u * 256 + t;
            int j = idx >> 6;
            dst[idx] = (unsigned short)bfr(__expf(src[idx] - smax[j]) / ssum[j]);
        }
    } else if (bx < 319) {
        // h_leaf(d,k)(x) = A x^2 + B x + C  (log2 domain)
        const int idx = (bx - 255) * 256 + t;
        float m = mu[idx], l = ls[idx];
        float is2 = __expf(-2.0f * l);
        ((float*)(ws + WS_A))[idx] = -0.5f * is2 * INV_LN2_F;
        ((float*)(ws + WS_B))[idx] = m * is2 * INV_LN2_F;
        ((float*)(ws + WS_C))[idx] = (-0.5f * m * m * is2 - l - LOG2PI_F) * INV_LN2_F;
    } else if (bx < 575) {
        const int bb = bx - 319;                    // batch range [8bb, 8bb+8)
        const int sd = scope[t];                    // lane t = leaf slot d
        float* xT = (float*)(ws + WS_XT);
        #pragma unroll
        for (int i = 0; i < 8; ++i) {
            int b = bb * 8 + i;
            xT[t * 2048 + b] = x[b * 256 + sd];
        }
    } else {
        // zero per-tile completion counters (ws is re-poisoned to 0xAA each call)
        if (t >= 64 && t < 192) ((int*)(ws + WS_CTR))[t - 64] = 0;
        if (t < 17) {
            Op* base = (Op*)(ws + WS_SCHED);
            Op* out; const int* lf[5]; int wb[5]; int root;
            if (t < 16) {
                root = t; out = base + t * 15;
                lf[1]=f1; lf[2]=f2; lf[3]=f3; lf[4]=f4;
                wb[1]=0; wb[2]=128; wb[3]=192; wb[4]=224;
            } else {
                root = 0; out = base + 240;          // tail tree: levels 5..8
                lf[1]=f5; lf[2]=f6; lf[3]=f7; lf[4]=f8;
                wb[1]=240; wb[2]=248; wb[3]=252; wb[4]=254;
            }
            int sl[8], sf[8], st[8]; int sp = 0, n = 0;
            sl[0] = 4; sf[0] = root; st[0] = 0; sp = 1;
            while (sp > 0) {
                int l = sl[sp-1], f = sf[sp-1];
                if (l == 1) {
                    out[n].w = (wb[1] + f) * 4096;
                    out[n].c0 = lf[1][2*f]; out[n].c1 = lf[1][2*f+1];
                    out[n].leaf = 1; n++; sp--;
                } else if (st[sp-1] == 0) {
                    st[sp-1] = 1;
                    sl[sp] = l-1; sf[sp] = lf[l][2*f]; st[sp] = 0; sp++;
                } else if (st[sp-1] == 1) {
                    st[sp-1] = 2;
                    sl[sp] = l-1; sf[sp] = lf[l][2*f+1]; st[sp] = 0; sp++;
                } else {
                    out[n].w = (wb[l] + f) * 4096;
                    out[n].c0 = 0; out[n].c1 = 0; out[n].leaf = 0; n++; sp--;
                }
            }
        }
    }
}

// ---------------------------------------------------------------------------
// Post-order DFS over one subtree; wave-autonomous; log2-domain values.
// gauss=true: leaf ops evaluate Gaussian pairs via (xT, A,B,C).
// gauss=false: leaf ops sum two node rows from in5 (node-id * 2048 rows).
// ---------------------------------------------------------------------------
__device__ __forceinline__ void run_tree(
    const Op* ops, int nops, bool gauss,
    const unsigned short* __restrict__ wbJ,
    const float* __restrict__ xT,
    const float* __restrict__ Ag, const float* __restrict__ Bg,
    const float* __restrict__ Cg,
    const float* __restrict__ in5,
    float* __restrict__ outg, int rowOff, float outScale,
    float* slotB, int b0, int m, int q)
{
    int4 bf[8];
    {
        const int4* wb4 = (const int4*)(wbJ + ops[0].w);
        #pragma unroll
        for (int jt = 0; jt < 4; ++jt)
            #pragma unroll
            for (int kh = 0; kh < 2; ++kh)
                bf[jt*2+kh] = wb4[(jt*16 + m) * 8 + kh*4 + q];
    }

    int vsp = 0;
    for (int io = 0; io < nops; ++io) {
        const Op op = ops[io];
        int curO, curP;
        if (op.leaf) { curO = vsp; curP = vsp; vsp++; }
        else         { curO = vsp - 2; curP = vsp - 1; vsp--; }
        float* slotO = slotB + curO * (16 * SSTR);
        float* slotP = slotB + curP * (16 * SSTR);

        // prefetch next op's B-frags
        int4 bn[8];
        {
            const int nxt = (io + 1 < nops) ? io + 1 : io;
            const int4* wb4 = (const int4*)(wbJ + ops[nxt].w);
            #pragma unroll
            for (int jt = 0; jt < 4; ++jt)
                #pragma unroll
                for (int kh = 0; kh < 2; ++kh)
                    bn[jt*2+kh] = wb4[(jt*16 + m) * 8 + kh*4 + q];
        }

        // ---- h (log2 domain), A-layout: lane holds h[m][kh*32 + q*8 + i]
        float hv[16];
        if (op.leaf) {
            if (gauss) {
                const int d0 = op.c0, d1 = op.c1;
                const float xv0 = xT[d0 * 2048 + b0 + m];
                const float xv1 = xT[d1 * 2048 + b0 + m];
                const float x0s = xv0 * xv0, x1s = xv1 * xv1;
                #pragma unroll
                for (int kh = 0; kh < 2; ++kh) {
                    const int kb = kh * 32 + q * 8;
                    F8 A0 = ld8(Ag + d0*64 + kb), B0 = ld8(Bg + d0*64 + kb);
                    F8 C0 = ld8(Cg + d0*64 + kb);
                    F8 A1 = ld8(Ag + d1*64 + kb), B1 = ld8(Bg + d1*64 + kb);
                    F8 C1 = ld8(Cg + d1*64 + kb);
                    #pragma unroll
                    for (int i = 0; i < 8; ++i) {
                        float t0 = fmaf(A0.v[i], x0s, C0.v[i]);
                        t0 = fmaf(B0.v[i], xv0, t0);
                        float t1 = fmaf(A1.v[i], x1s, C1.v[i]);
                        t1 = fmaf(B1.v[i], xv1, t1);
                        hv[kh*8+i] = t0 + t1;
                    }
                }
            } else {
                #pragma unroll
                for (int kh = 0; kh < 2; ++kh) {
                    const int kb = kh * 32 + q * 8;
                    F8 A = ld8(in5 + (op.c0 * 2048 + b0 + m) * 64 + kb);
                    F8 B = ld8(in5 + (op.c1 * 2048 + b0 + m) * 64 + kb);
                    #pragma unroll
                    for (int i = 0; i < 8; ++i) hv[kh*8+i] = A.v[i] + B.v[i];
                }
            }
        } else {
            #pragma unroll
            for (int kh = 0; kh < 2; ++kh) {
                const int base = m * SSTR + kh * 32 + q * 8;
                F8 A = ld8(slotO + base);
                F8 B = ld8(slotP + base);
                #pragma unroll
                for (int i = 0; i < 8; ++i) hv[kh*8+i] = A.v[i] + B.v[i];
            }
        }

        // ---- rowmax over k
        float m01 = fmaxf(hv[0], hv[1]),  m23 = fmaxf(hv[2], hv[3]);
        float m45 = fmaxf(hv[4], hv[5]),  m67 = fmaxf(hv[6], hv[7]);
        float m89 = fmaxf(hv[8], hv[9]),  mab = fmaxf(hv[10], hv[11]);
        float mcd = fmaxf(hv[12], hv[13]), mef = fmaxf(hv[14], hv[15]);
        float hm = fmaxf(fmaxf(fmaxf(m01, m23), fmaxf(m45, m67)),
                         fmaxf(fmaxf(m89, mab), fmaxf(mcd, mef)));
        hm = fmaxf(hm, __shfl_xor(hm, 16, 64));
        hm = fmaxf(hm, __shfl_xor(hm, 32, 64));

        // ---- p = exp2(h - m) -> bf16 A-frags (v_perm truncation pack)
        float e[16];
        #pragma unroll
        for (int i = 0; i < 16; ++i) e[i] = __builtin_amdgcn_exp2f(hv[i] - hm);
        int4 p0, p1;
        p0.x = __builtin_amdgcn_perm(__float_as_uint(e[1]),  __float_as_uint(e[0]),  0x07060302u);
        p0.y = __builtin_amdgcn_perm(__float_as_uint(e[3]),  __float_as_uint(e[2]),  0x07060302u);
        p0.z = __builtin_amdgcn_perm(__float_as_uint(e[5]),  __float_as_uint(e[4]),  0x07060302u);
        p0.w = __builtin_amdgcn_perm(__float_as_uint(e[7]),  __float_as_uint(e[6]),  0x07060302u);
        p1.x = __builtin_amdgcn_perm(__float_as_uint(e[9]),  __float_as_uint(e[8]),  0x07060302u);
        p1.y = __builtin_amdgcn_perm(__float_as_uint(e[11]), __float_as_uint(e[10]), 0x07060302u);
        p1.z = __builtin_amdgcn_perm(__float_as_uint(e[13]), __float_as_uint(e[12]), 0x07060302u);
        p1.w = __builtin_amdgcn_perm(__float_as_uint(e[15]), __float_as_uint(e[14]), 0x07060302u);
        bf16x8 a0 = *(bf16x8*)&p0;
        bf16x8 a1 = *(bf16x8*)&p1;

        // ---- 8x MFMA
        f32x4 acc[4];
        #pragma unroll
        for (int jt = 0; jt < 4; ++jt) {
            f32x4 z = {0.f, 0.f, 0.f, 0.f};
            z = __builtin_amdgcn_mfma_f32_16x16x32_bf16(a0, *(bf16x8*)&bf[jt*2+0], z, 0, 0, 0);
            z = __builtin_amdgcn_mfma_f32_16x16x32_bf16(a1, *(bf16x8*)&bf[jt*2+1], z, 0, 0, 0);
            acc[jt] = z;
        }

        float mr[4];
        #pragma unroll
        for (int r = 0; r < 4; ++r) mr[r] = __shfl(hm, q * 4 + r, 64);

        // ---- epilogue: out = log2(acc) + m ; C-layout row=4q+r, col=jt*16+m
        if (io == nops - 1) {
            #pragma unroll
            for (int jt = 0; jt < 4; ++jt)
                #pragma unroll
                for (int r = 0; r < 4; ++r)
                    outg[(rowOff + b0 + q*4 + r) * 64 + jt*16 + m] =
                        (__builtin_amdgcn_logf(acc[jt][r]) + mr[r]) * outScale;
        } else {
            #pragma unroll
            for (int jt = 0; jt < 4; ++jt)
                #pragma unroll
                for (int r = 0; r < 4; ++r)
                    slotO[(q*4 + r) * SSTR + jt*16 + m] =
                        __builtin_amdgcn_logf(acc[jt][r]) + mr[r];
            __builtin_amdgcn_wave_barrier();
            __builtin_amdgcn_s_waitcnt(0xC07F);   // lgkmcnt(0)
            __builtin_amdgcn_wave_barrier();
        }

        #pragma unroll
        for (int u = 0; u < 8; ++u) bf[u] = bn[u];
    }
}

// ---------------------------------------------------------------------------
// Fused circuit: 2048 one-wave blocks (s = bx%16 root, tile = bx/16).
// Producer part: levels 1-4 -> L4[s][b][k]; release-add ctr[tile].
// The s==0 block of each tile then acquire-spins to 16 and runs levels 5-8
// (tail schedule) from L4 to d_out. Residency: 17.4 KB LDS -> 9 blocks/CU,
// capacity 2304 >= 2048 -> all blocks resident -> spin cannot deadlock.
// ---------------------------------------------------------------------------
__global__ __launch_bounds__(64) void circuit_fused(
    const unsigned short* __restrict__ wbJ,
    const Op* __restrict__ schedG,
    const float* __restrict__ xT, const float* __restrict__ Ag,
    const float* __restrict__ Bg, const float* __restrict__ Cg,
    float* __restrict__ L4, float* __restrict__ dout,
    int* __restrict__ ctr)
{
    __shared__ float slot[4][16 * SSTR];
    __shared__ Op ops[32];

    const int t    = threadIdx.x;
    const int s    = blockIdx.x & 15;          // root (level-4 node)
    const int tile = blockIdx.x >> 4;          // batch tile
    const int b0   = tile * 16;

    if (t < 15)                  *(int4*)&ops[t] = ((const int4*)schedG)[s * 15 + t];
    else if (t >= 16 && t < 31)  *(int4*)&ops[t] = ((const int4*)schedG)[240 + (t - 16)];
    __syncthreads();

    const int m = t & 15;
    const int q = t >> 4;

    // ---- producer: levels 1..4 for (root s, tile)
    run_tree(&ops[0], 15, true, wbJ, xT, Ag, Bg, Cg,
             nullptr, L4, s * 2048, 1.0f, &slot[0][0], b0, m, q);

    __threadfence();                            // make L4 stores device-visible
    if (t == 0)
        __hip_atomic_fetch_add(&ctr[tile], 1, __ATOMIC_RELEASE, __HIP_MEMORY_SCOPE_AGENT);

    // ---- tail: levels 5..8 for this tile (one block per tile)
    if (s == 0) {
        if (t == 0) {
            while (__hip_atomic_load(&ctr[tile], __ATOMIC_ACQUIRE, __HIP_MEMORY_SCOPE_AGENT) < 16)
                __builtin_amdgcn_s_sleep(4);
        }
        __syncthreads();
        __threadfence();                        // acquire: invalidate stale caches
        run_tree(&ops[16], 15, false, wbJ, xT, Ag, Bg, Cg,
                 L4, dout, 0, LN2_F, &slot[0][0], b0, m, q);
    }
}

// ---------------------------------------------------------------------------
// d_in order: 0:x 1:mu 2:log_sigma 3:in_scope_idx, then fold_idx{l}, w{l}
// ---------------------------------------------------------------------------
extern "C" void kernel_launch(void* const* d_in, const int* in_sizes, int n_in,
                              void* d_out, int out_size, void* d_ws, size_t ws_size,
                              hipStream_t stream) {
    const float* x     = (const float*)d_in[0];
    const float* mu    = (const float*)d_in[1];
    const float* lsg   = (const float*)d_in[2];
    const int*   scope = (const int*)d_in[3];
    const int*   f1 = (const int*)d_in[4];   const float* w1 = (const float*)d_in[5];
    const int*   f2 = (const int*)d_in[6];   const float* w2 = (const float*)d_in[7];
    const int*   f3 = (const int*)d_in[8];   const float* w3 = (const float*)d_in[9];
    const int*   f4 = (const int*)d_in[10];  const float* w4 = (const float*)d_in[11];
    const int*   f5 = (const int*)d_in[12];  const float* w5 = (const float*)d_in[13];
    const int*   f6 = (const int*)d_in[14];  const float* w6 = (const float*)d_in[15];
    const int*   f7 = (const int*)d_in[16];  const float* w7 = (const float*)d_in[17];
    const int*   f8 = (const int*)d_in[18];  const float* w8 = (const float*)d_in[19];

    char* ws = (char*)d_ws;
    const unsigned short* wbJ = (const unsigned short*)(ws + WS_WBJ);
    const float* Ag  = (const float*)(ws + WS_A);
    const float* Bg  = (const float*)(ws + WS_B);
    const float* Cg  = (const float*)(ws + WS_C);
    const float* xT  = (const float*)(ws + WS_XT);
    const Op*    sch = (const Op*)(ws + WS_SCHED);
    int*         ctr = (int*)(ws + WS_CTR);
    float*       L4  = (float*)(ws + WS_L4);

    prep_kernel<<<576, 256, 0, stream>>>(w1, w2, w3, w4, w5, w6, w7, w8,
                                         mu, lsg, x, scope,
                                         f1, f2, f3, f4, f5, f6, f7, f8, ws);

    // levels 1..8 fused: 16 roots x 128 tiles; tail (L5-8) runs in-launch
    circuit_fused<<<2048, 64, 0, stream>>>(
        wbJ, sch, xT, Ag, Bg, Cg, L4, (float*)d_out, ctr);
}

// Round 6
// 183.880 us; speedup vs baseline: 1.7141x; 1.7141x over previous
//
#include <hip/hip_runtime.h>
#include <math.h>

#define LOG2PI_F  0.9189385332046727f
#define INV_LN2_F 1.4426950408889634f
#define LN2_F     0.6931471805599453f
#define SSTR      66          // stack slot row stride (floats)

typedef short bf16x8 __attribute__((ext_vector_type(8)));
typedef float f32x4  __attribute__((ext_vector_type(4)));

// meta = leaf(bit0) | srcSlotA<<2 | srcSlotB<<5 | dstSlot<<8  (dst 7 = global out)
struct __align__(16) Op { int w; int c0; int c1; int meta; };

// ---- workspace byte offsets -------------------------------------------------
#define WS_WBJ   0u          // bf16[255*4096] softmaxed weights, j-major
#define WS_A     2097152u    // float[256*64]  leaf coeff A (log2 domain)
#define WS_B     2162688u    // float[256*64]  leaf coeff B
#define WS_C     2228224u    // float[256*64]  leaf coeff C
#define WS_XT    2293760u    // float[256*2048] x gathered+transposed: xT[d][b]
#define WS_SCHED 4390912u    // Op[255]: K14 16x15 @0, K56 4x3 @240, K78 3 @252
#define WS_L4    4395008u    // float[16*2048*64] level-4 values (log2)
#define WS_L6    12783616u   // float[4*2048*64]  level-6 values (log2)

__device__ __forceinline__ short bfr(float f) {   // f32 -> bf16 RNE
    unsigned int u = __float_as_uint(f);
    u += 0x7fffu + ((u >> 16) & 1u);
    return (short)(u >> 16);
}

struct F8v { float v[8]; };
__device__ __forceinline__ F8v ld8(const float* p) {
    F8v r;
    float4 a = *(const float4*)p;
    float4 b = *(const float4*)(p + 4);
    r.v[0]=a.x; r.v[1]=a.y; r.v[2]=a.z; r.v[3]=a.w;
    r.v[4]=b.x; r.v[5]=b.y; r.v[6]=b.z; r.v[7]=b.w;
    return r;
}

__device__ __forceinline__ Op mk_leaf(int node, int c0, int c1, int dst) {
    Op o; o.w = node * 4096; o.c0 = c0; o.c1 = c1; o.meta = 1 | (dst << 8); return o;
}
__device__ __forceinline__ Op mk_mix(int wbase, int node, int sA, int sB, int dst) {
    Op o; o.w = (wbase + node) * 4096; o.c0 = 0; o.c1 = 0;
    o.meta = (sA << 2) | (sB << 5) | (dst << 8); return o;
}

// ---------------------------------------------------------------------------
// Prep: [0,255) softmax->bf16 j-major; [255,319) leaf quadratic coeffs;
// [319,575) x transpose/gather; 575: STACKLESS schedule build (folds staged
// to LDS; direct 4-level descent, constant indexing -> no scratch).
// ---------------------------------------------------------------------------
__global__ __launch_bounds__(256) void prep_kernel(
    const float* __restrict__ w1, const float* __restrict__ w2,
    const float* __restrict__ w3, const float* __restrict__ w4,
    const float* __restrict__ w5, const float* __restrict__ w6,
    const float* __restrict__ w7, const float* __restrict__ w8,
    const float* __restrict__ mu, const float* __restrict__ ls,
    const float* __restrict__ x,  const int* __restrict__ scope,
    const int* __restrict__ f1, const int* __restrict__ f2,
    const int* __restrict__ f3, const int* __restrict__ f4,
    const int* __restrict__ f5, const int* __restrict__ f6,
    const int* __restrict__ f7, const int* __restrict__ f8,
    char* __restrict__ ws)
{
    const int bx = blockIdx.x, t = threadIdx.x;
    if (bx < 255) {
        __shared__ float smax[64], ssum[64];
        const int g = bx;
        const float* src;
        if (g < 128)      src = w1 + g * 4096;
        else if (g < 192) src = w2 + (g - 128) * 4096;
        else if (g < 224) src = w3 + (g - 192) * 4096;
        else if (g < 240) src = w4 + (g - 224) * 4096;
        else if (g < 248) src = w5 + (g - 240) * 4096;
        else if (g < 252) src = w6 + (g - 248) * 4096;
        else              src = (g < 254) ? (w7 + (g - 252) * 4096) : w8;
        const int lane = t & 63, wv = t >> 6;
        for (int r = 0; r < 16; ++r) {
            int j = wv * 16 + r;
            float v = src[j * 64 + lane];
            float mx = v;
            for (int d = 1; d < 64; d <<= 1) mx = fmaxf(mx, __shfl_xor(mx, d, 64));
            float e = __expf(v - mx);
            float sm = e;
            for (int d = 1; d < 64; d <<= 1) sm += __shfl_xor(sm, d, 64);
            if (lane == 0) { smax[j] = mx; ssum[j] = sm; }
        }
        __syncthreads();
        unsigned short* dst = (unsigned short*)(ws + WS_WBJ) + g * 4096;
        for (int u = 0; u < 16; ++u) {
            int idx = u * 256 + t;
            int j = idx >> 6;
            dst[idx] = (unsigned short)bfr(__expf(src[idx] - smax[j]) / ssum[j]);
        }
    } else if (bx < 319) {
        // h_leaf(d,k)(x) = A x^2 + B x + C  (log2 domain)
        const int idx = (bx - 255) * 256 + t;
        float m = mu[idx], l = ls[idx];
        float is2 = __expf(-2.0f * l);
        ((float*)(ws + WS_A))[idx] = -0.5f * is2 * INV_LN2_F;
        ((float*)(ws + WS_B))[idx] = m * is2 * INV_LN2_F;
        ((float*)(ws + WS_C))[idx] = (-0.5f * m * m * is2 - l - LOG2PI_F) * INV_LN2_F;
    } else if (bx < 575) {
        const int bb = bx - 319;                    // batch range [8bb, 8bb+8)
        const int sd = scope[t];                    // lane t = leaf slot d
        float* xT = (float*)(ws + WS_XT);
        #pragma unroll
        for (int i = 0; i < 8; ++i) {
            int b = bb * 8 + i;
            xT[t * 2048 + b] = x[b * 256 + sd];
        }
    } else {
        // ---- schedule build, folds staged to LDS (no scratch, no stack)
        __shared__ int sf[512];
        for (int i = t; i < 256; i += 256) sf[i]        = f1[i];
        for (int i = t; i < 128; i += 256) sf[256 + i]  = f2[i];
        for (int i = t; i <  64; i += 256) sf[384 + i]  = f3[i];
        for (int i = t; i <  32; i += 256) sf[448 + i]  = f4[i];
        for (int i = t; i <  16; i += 256) sf[480 + i]  = f5[i];
        for (int i = t; i <   8; i += 256) sf[496 + i]  = f6[i];
        for (int i = t; i <   4; i += 256) sf[504 + i]  = f7[i];
        for (int i = t; i <   2; i += 256) sf[508 + i]  = f8[i];
        __syncthreads();
        const int* F1 = &sf[0];   const int* F2 = &sf[256];
        const int* F3 = &sf[384]; const int* F4 = &sf[448];
        const int* F5 = &sf[480]; const int* F6 = &sf[496];
        const int* F7 = &sf[504]; const int* F8 = &sf[508];
        Op* base = (Op*)(ws + WS_SCHED);
        if (t < 16) {
            // K14 subtree rooted at level-4 node t. Pair-ILP order, 6 slots:
            // (l0,l1)(l2,l3)(p0,p1)(l4,l5)(l6,l7)(p2,p3)(q0,q1)(root)
            Op* o = base + t * 15;
            int r0 = F4[2*t], r1 = F4[2*t+1];
            int P0 = F3[2*r0], P1 = F3[2*r0+1], P2 = F3[2*r1], P3 = F3[2*r1+1];
            int La = F2[2*P0], Lb = F2[2*P0+1], Lc = F2[2*P1], Ld = F2[2*P1+1];
            int Le = F2[2*P2], Lf = F2[2*P2+1], Lg = F2[2*P3], Lh = F2[2*P3+1];
            o[0]  = mk_leaf(La, F1[2*La], F1[2*La+1], 0);
            o[1]  = mk_leaf(Lb, F1[2*Lb], F1[2*Lb+1], 1);
            o[2]  = mk_leaf(Lc, F1[2*Lc], F1[2*Lc+1], 2);
            o[3]  = mk_leaf(Ld, F1[2*Ld], F1[2*Ld+1], 3);
            o[4]  = mk_mix(128, P0, 0, 1, 0);
            o[5]  = mk_mix(128, P1, 2, 3, 2);
            o[6]  = mk_leaf(Le, F1[2*Le], F1[2*Le+1], 1);
            o[7]  = mk_leaf(Lf, F1[2*Lf], F1[2*Lf+1], 3);
            o[8]  = mk_leaf(Lg, F1[2*Lg], F1[2*Lg+1], 4);
            o[9]  = mk_leaf(Lh, F1[2*Lh], F1[2*Lh+1], 5);
            o[10] = mk_mix(128, P2, 1, 3, 1);
            o[11] = mk_mix(128, P3, 4, 5, 4);
            o[12] = mk_mix(192, r0, 0, 2, 0);
            o[13] = mk_mix(192, r1, 1, 4, 1);
            o[14] = mk_mix(224, t,  0, 1, 7);
        } else if (t < 20) {
            // K56: level-6 root g; leaves read L4 node values
            const int g = t - 16;
            Op* o = base + 240 + g * 3;
            int c0 = F6[2*g], c1 = F6[2*g+1];            // level-5 node ids
            o[0] = mk_leaf(240 + c0, F5[2*c0], F5[2*c0+1], 0);
            o[1] = mk_leaf(240 + c1, F5[2*c1], F5[2*c1+1], 1);
            o[2] = mk_mix(248, g, 0, 1, 7);
        } else if (t == 20) {
            // K78: level-8 root; leaves read L6 node values
            Op* o = base + 252;
            int n0 = F8[0], n1 = F8[1];                  // level-7 node ids
            o[0] = mk_leaf(252 + n0, F7[2*n0], F7[2*n0+1], 0);
            o[1] = mk_leaf(252 + n1, F7[2*n1], F7[2*n1+1], 1);
            o[2] = mk_mix(254, 0, 0, 1, 7);
        }
    }
}

// ---------------------------------------------------------------------------
// h-phase for one op (log2 domain, A-layout: lane (q,m) holds h[m][kh*32+q*8+i])
// ---------------------------------------------------------------------------
template<bool GAUSS>
__device__ __forceinline__ void op_h(
    const Op& op,
    const float* __restrict__ xT, const float* __restrict__ Ag,
    const float* __restrict__ Bg, const float* __restrict__ Cg,
    const float* __restrict__ in5,
    const float* slotM, int b0, int m, int q, float hv[16])
{
    if (op.meta & 1) {
        if (GAUSS) {
            const int d0 = op.c0, d1 = op.c1;
            const float xv0 = xT[d0 * 2048 + b0 + m];
            const float xv1 = xT[d1 * 2048 + b0 + m];
            const float x0s = xv0 * xv0, x1s = xv1 * xv1;
            #pragma unroll
            for (int kh = 0; kh < 2; ++kh) {
                const int kb = kh * 32 + q * 8;
                F8v A0 = ld8(Ag + d0*64 + kb), B0 = ld8(Bg + d0*64 + kb);
                F8v C0 = ld8(Cg + d0*64 + kb);
                F8v A1 = ld8(Ag + d1*64 + kb), B1 = ld8(Bg + d1*64 + kb);
                F8v C1 = ld8(Cg + d1*64 + kb);
                #pragma unroll
                for (int i = 0; i < 8; ++i) {
                    float t0 = fmaf(A0.v[i], x0s, C0.v[i]);
                    t0 = fmaf(B0.v[i], xv0, t0);
                    float t1 = fmaf(A1.v[i], x1s, C1.v[i]);
                    t1 = fmaf(B1.v[i], xv1, t1);
                    hv[kh*8+i] = t0 + t1;
                }
            }
        } else {
            #pragma unroll
            for (int kh = 0; kh < 2; ++kh) {
                const int kb = kh * 32 + q * 8;
                F8v A = ld8(in5 + (op.c0 * 2048 + b0 + m) * 64 + kb);
                F8v B = ld8(in5 + (op.c1 * 2048 + b0 + m) * 64 + kb);
                #pragma unroll
                for (int i = 0; i < 8; ++i) hv[kh*8+i] = A.v[i] + B.v[i];
            }
        }
    } else {
        const int sA = (op.meta >> 2) & 7, sB = (op.meta >> 5) & 7;
        const float* SA = slotM + sA * (16 * SSTR) + m * SSTR;
        const float* SB = slotM + sB * (16 * SSTR) + m * SSTR;
        #pragma unroll
        for (int kh = 0; kh < 2; ++kh) {
            const int kb = kh * 32 + q * 8;
            F8v A = ld8(SA + kb);
            F8v B = ld8(SB + kb);
            #pragma unroll
            for (int i = 0; i < 8; ++i) hv[kh*8+i] = A.v[i] + B.v[i];
        }
    }
}

__device__ __forceinline__ float rmax16(const float hv[16]) {
    float m01 = fmaxf(hv[0], hv[1]),  m23 = fmaxf(hv[2], hv[3]);
    float m45 = fmaxf(hv[4], hv[5]),  m67 = fmaxf(hv[6], hv[7]);
    float m89 = fmaxf(hv[8], hv[9]),  mab = fmaxf(hv[10], hv[11]);
    float mcd = fmaxf(hv[12], hv[13]), mef = fmaxf(hv[14], hv[15]);
    float hm = fmaxf(fmaxf(fmaxf(m01, m23), fmaxf(m45, m67)),
                     fmaxf(fmaxf(m89, mab), fmaxf(mcd, mef)));
    hm = fmaxf(hm, __shfl_xor(hm, 16, 64));
    hm = fmaxf(hm, __shfl_xor(hm, 32, 64));
    return hm;
}

__device__ __forceinline__ void pack_p(const float hv[16], float hm,
                                       bf16x8& a0, bf16x8& a1) {
    float e[16];
    #pragma unroll
    for (int i = 0; i < 16; ++i) e[i] = __builtin_amdgcn_exp2f(hv[i] - hm);
    int4 p0, p1;
    p0.x = __builtin_amdgcn_perm(__float_as_uint(e[1]),  __float_as_uint(e[0]),  0x07060302u);
    p0.y = __builtin_amdgcn_perm(__float_as_uint(e[3]),  __float_as_uint(e[2]),  0x07060302u);
    p0.z = __builtin_amdgcn_perm(__float_as_uint(e[5]),  __float_as_uint(e[4]),  0x07060302u);
    p0.w = __builtin_amdgcn_perm(__float_as_uint(e[7]),  __float_as_uint(e[6]),  0x07060302u);
    p1.x = __builtin_amdgcn_perm(__float_as_uint(e[9]),  __float_as_uint(e[8]),  0x07060302u);
    p1.y = __builtin_amdgcn_perm(__float_as_uint(e[11]), __float_as_uint(e[10]), 0x07060302u);
    p1.z = __builtin_amdgcn_perm(__float_as_uint(e[13]), __float_as_uint(e[12]), 0x07060302u);
    p1.w = __builtin_amdgcn_perm(__float_as_uint(e[15]), __float_as_uint(e[14]), 0x07060302u);
    a0 = *(bf16x8*)&p0;
    a1 = *(bf16x8*)&p1;
}

// ---------------------------------------------------------------------------
// Pair-ILP circuit kernel: 1 wave per block, 16-row tile, ops processed in
// independent PAIRS (schedule guarantees no intra-pair deps) -> two latency
// chains overlap; one LDS fence per pair instead of per op. 6-slot LDS stack.
// ---------------------------------------------------------------------------
template<bool GAUSS>
__global__ __launch_bounds__(64) void circuit_lp(
    const unsigned short* __restrict__ wbJ,
    const Op* __restrict__ schedG, int nops, int nsub,
    const float* __restrict__ xT, const float* __restrict__ Ag,
    const float* __restrict__ Bg, const float* __restrict__ Cg,
    const float* __restrict__ in5,
    float* __restrict__ outg, float outScale)
{
    __shared__ float slotM[6 * 16 * SSTR];
    __shared__ Op ops[15];

    const int t  = threadIdx.x;
    const int s  = blockIdx.x % nsub;
    const int b0 = (blockIdx.x / nsub) * 16;
    if (t < nops) *(int4*)&ops[t] = ((const int4*)(schedG + s * nops))[t];
    __syncthreads();

    const int m = t & 15;
    const int q = t >> 4;
    const int rowOff = s * 2048;

    for (int io = 0; io < nops; io += 2) {
        const Op opA = ops[io];
        const Op opB = ops[(io + 1 < nops) ? io + 1 : io];   // solo tail: dup (benign)

        // ---- B-frags for both ops (issued early, consumed after h/max/exp)
        int4 bfA[8], bfB[8];
        {
            const int4* wA = (const int4*)(wbJ + opA.w);
            const int4* wB = (const int4*)(wbJ + opB.w);
            #pragma unroll
            for (int jt = 0; jt < 4; ++jt)
                #pragma unroll
                for (int kh = 0; kh < 2; ++kh) {
                    bfA[jt*2+kh] = wA[(jt*16 + m) * 8 + kh*4 + q];
                    bfB[jt*2+kh] = wB[(jt*16 + m) * 8 + kh*4 + q];
                }
        }

        // ---- two independent h chains
        float hA[16], hB[16];
        op_h<GAUSS>(opA, xT, Ag, Bg, Cg, in5, slotM, b0, m, q, hA);
        op_h<GAUSS>(opB, xT, Ag, Bg, Cg, in5, slotM, b0, m, q, hB);

        const float hmA = rmax16(hA);
        const float hmB = rmax16(hB);

        bf16x8 aA0, aA1, aB0, aB1;
        pack_p(hA, hmA, aA0, aA1);
        pack_p(hB, hmB, aB0, aB1);

        f32x4 accA[4], accB[4];
        #pragma unroll
        for (int jt = 0; jt < 4; ++jt) {
            f32x4 zA = {0.f, 0.f, 0.f, 0.f};
            zA = __builtin_amdgcn_mfma_f32_16x16x32_bf16(aA0, *(bf16x8*)&bfA[jt*2+0], zA, 0, 0, 0);
            zA = __builtin_amdgcn_mfma_f32_16x16x32_bf16(aA1, *(bf16x8*)&bfA[jt*2+1], zA, 0, 0, 0);
            accA[jt] = zA;
            f32x4 zB = {0.f, 0.f, 0.f, 0.f};
            zB = __builtin_amdgcn_mfma_f32_16x16x32_bf16(aB0, *(bf16x8*)&bfB[jt*2+0], zB, 0, 0, 0);
            zB = __builtin_amdgcn_mfma_f32_16x16x32_bf16(aB1, *(bf16x8*)&bfB[jt*2+1], zB, 0, 0, 0);
            accB[jt] = zB;
        }

        float mrA[4], mrB[4];
        #pragma unroll
        for (int r = 0; r < 4; ++r) {
            mrA[r] = __shfl(hmA, q * 4 + r, 64);
            mrB[r] = __shfl(hmB, q * 4 + r, 64);
        }

        // ---- epilogues (A then B); C-layout row=4q+r, col=jt*16+m
        {
            const int dA = (opA.meta >> 8) & 7;
            if (dA == 7) {
                #pragma unroll
                for (int jt = 0; jt < 4; ++jt)
                    #pragma unroll
                    for (int r = 0; r < 4; ++r)
                        outg[(rowOff + b0 + q*4 + r) * 64 + jt*16 + m] =
                            (__builtin_amdgcn_logf(accA[jt][r]) + mrA[r]) * outScale;
            } else {
                float* S = slotM + dA * (16 * SSTR);
                #pragma unroll
                for (int jt = 0; jt < 4; ++jt)
                    #pragma unroll
                    for (int r = 0; r < 4; ++r)
                        S[(q*4 + r) * SSTR + jt*16 + m] =
                            __builtin_amdgcn_logf(accA[jt][r]) + mrA[r];
            }
            const int dB = (opB.meta >> 8) & 7;
            if (dB == 7) {
                #pragma unroll
                for (int jt = 0; jt < 4; ++jt)
                    #pragma unroll
                    for (int r = 0; r < 4; ++r)
                        outg[(rowOff + b0 + q*4 + r) * 64 + jt*16 + m] =
                            (__builtin_amdgcn_logf(accB[jt][r]) + mrB[r]) * outScale;
            } else {
                float* S = slotM + dB * (16 * SSTR);
                #pragma unroll
                for (int jt = 0; jt < 4; ++jt)
                    #pragma unroll
                    for (int r = 0; r < 4; ++r)
                        S[(q*4 + r) * SSTR + jt*16 + m] =
                            __builtin_amdgcn_logf(accB[jt][r]) + mrB[r];
            }
        }
        __builtin_amdgcn_wave_barrier();
        __builtin_amdgcn_s_waitcnt(0xC07F);   // lgkmcnt(0): slot writes visible
        __builtin_amdgcn_wave_barrier();
    }
}

// ---------------------------------------------------------------------------
// d_in order: 0:x 1:mu 2:log_sigma 3:in_scope_idx, then fold_idx{l}, w{l}
// ---------------------------------------------------------------------------
extern "C" void kernel_launch(void* const* d_in, const int* in_sizes, int n_in,
                              void* d_out, int out_size, void* d_ws, size_t ws_size,
                              hipStream_t stream) {
    const float* x     = (const float*)d_in[0];
    const float* mu    = (const float*)d_in[1];
    const float* lsg   = (const float*)d_in[2];
    const int*   scope = (const int*)d_in[3];
    const int*   f1 = (const int*)d_in[4];   const float* w1 = (const float*)d_in[5];
    const int*   f2 = (const int*)d_in[6];   const float* w2 = (const float*)d_in[7];
    const int*   f3 = (const int*)d_in[8];   const float* w3 = (const float*)d_in[9];
    const int*   f4 = (const int*)d_in[10];  const float* w4 = (const float*)d_in[11];
    const int*   f5 = (const int*)d_in[12];  const float* w5 = (const float*)d_in[13];
    const int*   f6 = (const int*)d_in[14];  const float* w6 = (const float*)d_in[15];
    const int*   f7 = (const int*)d_in[16];  const float* w7 = (const float*)d_in[17];
    const int*   f8 = (const int*)d_in[18];  const float* w8 = (const float*)d_in[19];

    char* ws = (char*)d_ws;
    const unsigned short* wbJ = (const unsigned short*)(ws + WS_WBJ);
    const float* Ag  = (const float*)(ws + WS_A);
    const float* Bg  = (const float*)(ws + WS_B);
    const float* Cg  = (const float*)(ws + WS_C);
    const float* xT  = (const float*)(ws + WS_XT);
    const Op*    sch = (const Op*)(ws + WS_SCHED);
    float*       L4  = (float*)(ws + WS_L4);
    float*       L6  = (float*)(ws + WS_L6);

    prep_kernel<<<576, 256, 0, stream>>>(w1, w2, w3, w4, w5, w6, w7, w8,
                                         mu, lsg, x, scope,
                                         f1, f2, f3, f4, f5, f6, f7, f8, ws);

    // levels 1..4: 16 roots x 128 tiles, pair-ILP
    circuit_lp<true><<<2048, 64, 0, stream>>>(
        wbJ, sch, 15, 16,
        xT, Ag, Bg, Cg,
        nullptr, L4, 1.0f);

    // levels 5..6: 4 roots x 128 tiles
    circuit_lp<false><<<512, 64, 0, stream>>>(
        wbJ, sch + 240, 3, 4,
        nullptr, nullptr, nullptr, nullptr,
        L4, L6, 1.0f);

    // levels 7..8: 128 tiles, final output scaled back to natural log
    circuit_lp<false><<<128, 64, 0, stream>>>(
        wbJ, sch + 252, 3, 1,
        nullptr, nullptr, nullptr, nullptr,
        L6, (float*)d_out, LN2_F);
}

// Round 8
// 168.900 us; speedup vs baseline: 1.8661x; 1.0887x over previous
//
#include <hip/hip_runtime.h>
#include <math.h>

#define LOG2PI_F  0.9189385332046727f
#define INV_LN2_F 1.4426950408889634f
#define LN2_F     0.6931471805599453f
#define SROW      80          // slot row stride in shorts (160B, 16B-aligned rows)

typedef short bf16x8 __attribute__((ext_vector_type(8)));
typedef float f32x4  __attribute__((ext_vector_type(4)));

// meta = leaf(bit0) | srcSlotA<<2 | srcSlotB<<5 | dstSlot<<8 (4 bits; 15 = global out)
struct __align__(16) Op { int w; int c0; int c1; int meta; };

// ---- workspace byte offsets -------------------------------------------------
#define WS_WBJ   0u          // bf16[255*4096] softmaxed weights, j-major
#define WS_A     2097152u    // float[256*64]  leaf coeff A (log2 domain)
#define WS_B     2162688u    // float[256*64]  leaf coeff B
#define WS_C     2228224u    // float[256*64]  leaf coeff C
#define WS_XT    2293760u    // float[256*2048] x gathered+transposed: xT[d][b]
#define WS_SCHED 4390912u    // Op[16*15 @0 .. K14, 15 @240 .. tail L5-8]
#define WS_L4A   4395008u    // bf16[16*2048*64] level-4 acc values
#define WS_L4M   8589312u    // float[16*2048]   level-4 row scales (log2)

__device__ __forceinline__ short bfr(float f) {   // f32 -> bf16 RNE
    unsigned int u = __float_as_uint(f);
    u += 0x7fffu + ((u >> 16) & 1u);
    return (short)(u >> 16);
}

struct F8v { float v[8]; };
__device__ __forceinline__ F8v ld8(const float* p) {
    F8v r;
    float4 a = *(const float4*)p;
    float4 b = *(const float4*)(p + 4);
    r.v[0]=a.x; r.v[1]=a.y; r.v[2]=a.z; r.v[3]=a.w;
    r.v[4]=b.x; r.v[5]=b.y; r.v[6]=b.z; r.v[7]=b.w;
    return r;
}

__device__ __forceinline__ void up8(int4 v, float* o) {   // 8 bf16 -> f32
    o[0] = __uint_as_float(((unsigned)v.x) << 16);
    o[1] = __uint_as_float(((unsigned)v.x) & 0xffff0000u);
    o[2] = __uint_as_float(((unsigned)v.y) << 16);
    o[3] = __uint_as_float(((unsigned)v.y) & 0xffff0000u);
    o[4] = __uint_as_float(((unsigned)v.z) << 16);
    o[5] = __uint_as_float(((unsigned)v.z) & 0xffff0000u);
    o[6] = __uint_as_float(((unsigned)v.w) << 16);
    o[7] = __uint_as_float(((unsigned)v.w) & 0xffff0000u);
}

__device__ __forceinline__ Op mk_leaf(int node, int c0, int c1, int dst) {
    Op o; o.w = node * 4096; o.c0 = c0; o.c1 = c1; o.meta = 1 | (dst << 8); return o;
}
__device__ __forceinline__ Op mk_mix(int wslot, int sA, int sB, int dst) {
    Op o; o.w = wslot * 4096; o.c0 = 0; o.c1 = 0;
    o.meta = (sA << 2) | (sB << 5) | (dst << 8); return o;
}

__device__ __forceinline__ float rmax16(const float hv[16]) {
    float m01 = fmaxf(hv[0], hv[1]),  m23 = fmaxf(hv[2], hv[3]);
    float m45 = fmaxf(hv[4], hv[5]),  m67 = fmaxf(hv[6], hv[7]);
    float m89 = fmaxf(hv[8], hv[9]),  mab = fmaxf(hv[10], hv[11]);
    float mcd = fmaxf(hv[12], hv[13]), mef = fmaxf(hv[14], hv[15]);
    float hm = fmaxf(fmaxf(fmaxf(m01, m23), fmaxf(m45, m67)),
                     fmaxf(fmaxf(m89, mab), fmaxf(mcd, mef)));
    hm = fmaxf(hm, __shfl_xor(hm, 16, 64));
    hm = fmaxf(hm, __shfl_xor(hm, 32, 64));
    return hm;
}

__device__ __forceinline__ void pack_p(const float e[16], bf16x8& a0, bf16x8& a1) {
    int4 p0, p1;
    p0.x = __builtin_amdgcn_perm(__float_as_uint(e[1]),  __float_as_uint(e[0]),  0x07060302u);
    p0.y = __builtin_amdgcn_perm(__float_as_uint(e[3]),  __float_as_uint(e[2]),  0x07060302u);
    p0.z = __builtin_amdgcn_perm(__float_as_uint(e[5]),  __float_as_uint(e[4]),  0x07060302u);
    p0.w = __builtin_amdgcn_perm(__float_as_uint(e[7]),  __float_as_uint(e[6]),  0x07060302u);
    p1.x = __builtin_amdgcn_perm(__float_as_uint(e[9]),  __float_as_uint(e[8]),  0x07060302u);
    p1.y = __builtin_amdgcn_perm(__float_as_uint(e[11]), __float_as_uint(e[10]), 0x07060302u);
    p1.z = __builtin_amdgcn_perm(__float_as_uint(e[13]), __float_as_uint(e[12]), 0x07060302u);
    p1.w = __builtin_amdgcn_perm(__float_as_uint(e[15]), __float_as_uint(e[14]), 0x07060302u);
    a0 = *(bf16x8*)&p0;
    a1 = *(bf16x8*)&p1;
}

// ---------------------------------------------------------------------------
// Prep: [0,255) softmax->bf16 j-major; [255,319) leaf quadratic coeffs;
// [319,575) x transpose/gather; 575: schedule build (stackless).
// ---------------------------------------------------------------------------
__global__ __launch_bounds__(256) void prep_kernel(
    const float* __restrict__ w1, const float* __restrict__ w2,
    const float* __restrict__ w3, const float* __restrict__ w4,
    const float* __restrict__ w5, const float* __restrict__ w6,
    const float* __restrict__ w7, const float* __restrict__ w8,
    const float* __restrict__ mu, const float* __restrict__ ls,
    const float* __restrict__ x,  const int* __restrict__ scope,
    const int* __restrict__ f1, const int* __restrict__ f2,
    const int* __restrict__ f3, const int* __restrict__ f4,
    const int* __restrict__ f5, const int* __restrict__ f6,
    const int* __restrict__ f7, const int* __restrict__ f8,
    char* __restrict__ ws)
{
    const int bx = blockIdx.x, t = threadIdx.x;
    if (bx < 255) {
        __shared__ float smax[64], ssum[64];
        const int g = bx;
        const float* src;
        if (g < 128)      src = w1 + g * 4096;
        else if (g < 192) src = w2 + (g - 128) * 4096;
        else if (g < 224) src = w3 + (g - 192) * 4096;
        else if (g < 240) src = w4 + (g - 224) * 4096;
        else if (g < 248) src = w5 + (g - 240) * 4096;
        else if (g < 252) src = w6 + (g - 248) * 4096;
        else              src = (g < 254) ? (w7 + (g - 252) * 4096) : w8;
        const int lane = t & 63, wv = t >> 6;
        for (int r = 0; r < 16; ++r) {
            int j = wv * 16 + r;
            float v = src[j * 64 + lane];
            float mx = v;
            for (int d = 1; d < 64; d <<= 1) mx = fmaxf(mx, __shfl_xor(mx, d, 64));
            float e = __expf(v - mx);
            float sm = e;
            for (int d = 1; d < 64; d <<= 1) sm += __shfl_xor(sm, d, 64);
            if (lane == 0) { smax[j] = mx; ssum[j] = sm; }
        }
        __syncthreads();
        unsigned short* dst = (unsigned short*)(ws + WS_WBJ) + g * 4096;
        for (int u = 0; u < 16; ++u) {
            int idx = u * 256 + t;
            int j = idx >> 6;
            dst[idx] = (unsigned short)bfr(__expf(src[idx] - smax[j]) / ssum[j]);
        }
    } else if (bx < 319) {
        // h_leaf(d,k)(x) = A x^2 + B x + C  (log2 domain)
        const int idx = (bx - 255) * 256 + t;
        float m = mu[idx], l = ls[idx];
        float is2 = __expf(-2.0f * l);
        ((float*)(ws + WS_A))[idx] = -0.5f * is2 * INV_LN2_F;
        ((float*)(ws + WS_B))[idx] = m * is2 * INV_LN2_F;
        ((float*)(ws + WS_C))[idx] = (-0.5f * m * m * is2 - l - LOG2PI_F) * INV_LN2_F;
    } else if (bx < 575) {
        const int bb = bx - 319;                    // batch range [8bb, 8bb+8)
        const int sd = scope[t];                    // lane t = leaf slot d
        float* xT = (float*)(ws + WS_XT);
        #pragma unroll
        for (int i = 0; i < 8; ++i) {
            int b = bb * 8 + i;
            xT[t * 2048 + b] = x[b * 256 + sd];
        }
    } else {
        // ---- schedule build, folds staged to LDS (no scratch, no stack)
        __shared__ int sf[512];
        for (int i = t; i < 256; i += 256) sf[i]        = f1[i];
        for (int i = t; i < 128; i += 256) sf[256 + i]  = f2[i];
        for (int i = t; i <  64; i += 256) sf[384 + i]  = f3[i];
        for (int i = t; i <  32; i += 256) sf[448 + i]  = f4[i];
        for (int i = t; i <  16; i += 256) sf[480 + i]  = f5[i];
        for (int i = t; i <   8; i += 256) sf[496 + i]  = f6[i];
        for (int i = t; i <   4; i += 256) sf[504 + i]  = f7[i];
        for (int i = t; i <   2; i += 256) sf[508 + i]  = f8[i];
        __syncthreads();
        const int* F1 = &sf[0];   const int* F2 = &sf[256];
        const int* F3 = &sf[384]; const int* F4 = &sf[448];
        const int* F5 = &sf[480]; const int* F6 = &sf[496];
        const int* F7 = &sf[504]; const int* F8 = &sf[508];
        Op* base = (Op*)(ws + WS_SCHED);
        if (t < 16) {
            // K14 subtree rooted at level-4 node t. Pair-ILP order, 6 slots.
            Op* o = base + t * 15;
            int r0 = F4[2*t], r1 = F4[2*t+1];
            int P0 = F3[2*r0], P1 = F3[2*r0+1], P2 = F3[2*r1], P3 = F3[2*r1+1];
            int La = F2[2*P0], Lb = F2[2*P0+1], Lc = F2[2*P1], Ld = F2[2*P1+1];
            int Le = F2[2*P2], Lf = F2[2*P2+1], Lg = F2[2*P3], Lh = F2[2*P3+1];
            o[0]  = mk_leaf(La, F1[2*La], F1[2*La+1], 0);
            o[1]  = mk_leaf(Lb, F1[2*Lb], F1[2*Lb+1], 1);
            o[2]  = mk_leaf(Lc, F1[2*Lc], F1[2*Lc+1], 2);
            o[3]  = mk_leaf(Ld, F1[2*Ld], F1[2*Ld+1], 3);
            o[4]  = mk_mix(128 + P0, 0, 1, 0);
            o[5]  = mk_mix(128 + P1, 2, 3, 2);
            o[6]  = mk_leaf(Le, F1[2*Le], F1[2*Le+1], 1);
            o[7]  = mk_leaf(Lf, F1[2*Lf], F1[2*Lf+1], 3);
            o[8]  = mk_leaf(Lg, F1[2*Lg], F1[2*Lg+1], 4);
            o[9]  = mk_leaf(Lh, F1[2*Lh], F1[2*Lh+1], 5);
            o[10] = mk_mix(128 + P2, 1, 3, 1);
            o[11] = mk_mix(128 + P3, 4, 5, 4);
            o[12] = mk_mix(192 + r0, 0, 2, 0);
            o[13] = mk_mix(192 + r1, 1, 4, 1);
            o[14] = mk_mix(224 + t,  0, 1, 15);       // 15 = global out sentinel
        } else if (t == 16) {
            // Tail tree, levels 5..8 (15 ops, pair-safe order, 8 slots 0..7).
            Op* o = base + 240;
            #pragma unroll
            for (int i = 0; i < 8; ++i)
                o[i] = mk_leaf(240 + i, F5[2*i], F5[2*i+1], i);
            #pragma unroll
            for (int g6 = 0; g6 < 4; ++g6)
                o[8 + g6] = mk_mix(248 + g6, F6[2*g6], F6[2*g6+1], F6[2*g6]);
            #pragma unroll
            for (int u = 0; u < 2; ++u) {
                int sA = F6[2 * F7[2*u]];        // slot written by L6 op F7[2u]
                int sB = F6[2 * F7[2*u+1]];
                o[12 + u] = mk_mix(252 + u, sA, sB, sA);
            }
            int sA = F6[2 * F7[2 * F8[0]]];      // slot of L7 op F8[0]
            int sB = F6[2 * F7[2 * F8[1]]];
            o[14] = mk_mix(254, sA, sB, 15);          // 15 = global out sentinel
        }
    }
}

// ---------------------------------------------------------------------------
// Phase: compute the MFMA input p[16] (linear, max in [1,2)) and row scale
// Mrow for one op. MODE 0 leaf = Gaussian (log2 quad + exp2); MODE 1 leaf =
// product of two global (acc,M) node values; internal = product of two LDS
// slot values. Products need NO transcendentals: renormalize by the exact
// power-of-two exponent of the row max.
// ---------------------------------------------------------------------------
template<int MODE>
__device__ __forceinline__ void op_phase(
    const Op op,
    const float* __restrict__ xT, const float* __restrict__ Ag,
    const float* __restrict__ Bg, const float* __restrict__ Cg,
    const unsigned short* __restrict__ inAcc, const float* __restrict__ inM,
    const unsigned short* slotS, const float* Mslot,
    int b0, int m, int q, float p[16], float& Mrow)
{
    if ((op.meta & 1) && MODE == 0) {
        // Gaussian leaf pair: h log2-domain, p = exp2(h - rowmax)
        const int d0 = op.c0, d1 = op.c1;
        const float xv0 = xT[d0 * 2048 + b0 + m];
        const float xv1 = xT[d1 * 2048 + b0 + m];
        const float x0s = xv0 * xv0, x1s = xv1 * xv1;
        float hv[16];
        #pragma unroll
        for (int kh = 0; kh < 2; ++kh) {
            const int kb = kh * 32 + q * 8;
            F8v A0 = ld8(Ag + d0*64 + kb), B0 = ld8(Bg + d0*64 + kb);
            F8v C0 = ld8(Cg + d0*64 + kb);
            F8v A1 = ld8(Ag + d1*64 + kb), B1 = ld8(Bg + d1*64 + kb);
            F8v C1 = ld8(Cg + d1*64 + kb);
            #pragma unroll
            for (int i = 0; i < 8; ++i) {
                float t0 = fmaf(A0.v[i], x0s, C0.v[i]);
                t0 = fmaf(B0.v[i], xv0, t0);
                float t1 = fmaf(A1.v[i], x1s, C1.v[i]);
                t1 = fmaf(B1.v[i], xv1, t1);
                hv[kh*8+i] = t0 + t1;
            }
        }
        const float hm = rmax16(hv);
        #pragma unroll
        for (int i = 0; i < 16; ++i) p[i] = __builtin_amdgcn_exp2f(hv[i] - hm);
        Mrow = hm;
        return;
    }

    // ---- product path: two (acc, M) sources
    float av[16], bv[16];
    float MA, MB;
    if (op.meta & 1) {
        // MODE 1 leaf: global L4 nodes op.c0 / op.c1, row b0+m
        const int4* A4 = (const int4*)(inAcc + (size_t)(op.c0 * 2048 + b0 + m) * 64);
        const int4* B4 = (const int4*)(inAcc + (size_t)(op.c1 * 2048 + b0 + m) * 64);
        int4 a0 = A4[q], a1 = A4[4 + q];
        int4 b0v = B4[q], b1v = B4[4 + q];
        up8(a0, av); up8(a1, av + 8);
        up8(b0v, bv); up8(b1v, bv + 8);
        MA = inM[op.c0 * 2048 + b0 + m];
        MB = inM[op.c1 * 2048 + b0 + m];
    } else {
        const int sA = (op.meta >> 2) & 7, sB = (op.meta >> 5) & 7;
        const int4* A4 = (const int4*)(slotS + sA * 16 * SROW + m * SROW);
        const int4* B4 = (const int4*)(slotS + sB * 16 * SROW + m * SROW);
        int4 a0 = A4[q], a1 = A4[4 + q];      // halves at +0 and +64 shorts
        int4 b0v = B4[q], b1v = B4[4 + q];
        up8(a0, av); up8(a1, av + 8);
        up8(b0v, bv); up8(b1v, bv + 8);
        MA = Mslot[sA * 16 + m];
        MB = Mslot[sB * 16 + m];
    }
    float pv[16];
    #pragma unroll
    for (int i = 0; i < 16; ++i) pv[i] = av[i] * bv[i];
    const float rm = rmax16(pv);
    const int e = (int)((__float_as_uint(rm) >> 23) & 0xFF) - 127;
    #pragma unroll
    for (int i = 0; i < 16; ++i) p[i] = ldexpf(pv[i], -e);   // exact scaling
    Mrow = MA + MB + (float)e;
}

// ---------------------------------------------------------------------------
// Pair-ILP circuit kernel: 1 wave per block, 16-row tile, ops in independent
// pairs (one LDS fence per pair). Slots hold bf16 acc + f32 row scale — no
// log/exp on internal edges. MODE 0: K14 (Gauss leaves, out = L4 acc+M).
// MODE 1: tail L5-8 (global-product leaves, out = d_out natural log).
// ---------------------------------------------------------------------------
template<int MODE>
__global__ __launch_bounds__(64) void circuit_x(
    const unsigned short* __restrict__ wbJ,
    const Op* __restrict__ schedG, int nops, int nsub,
    const float* __restrict__ xT, const float* __restrict__ Ag,
    const float* __restrict__ Bg, const float* __restrict__ Cg,
    const unsigned short* __restrict__ inAcc, const float* __restrict__ inM,
    unsigned short* __restrict__ outAcc, float* __restrict__ outM,
    float* __restrict__ outLog)
{
    constexpr int NSLOT = (MODE == 0) ? 6 : 8;
    __shared__ __align__(16) unsigned short slotS[NSLOT * 16 * SROW];
    __shared__ float Mslot[NSLOT * 16];
    __shared__ Op ops[16];

    const int t  = threadIdx.x;
    const int s  = blockIdx.x % nsub;
    const int b0 = (blockIdx.x / nsub) * 16;
    if (t < nops) *(int4*)&ops[t] = ((const int4*)(schedG + s * nops))[t];
    __syncthreads();

    const int m = t & 15;
    const int q = t >> 4;
    const int rowOff = s * 2048;

    for (int io = 0; io < nops; io += 2) {
        const Op opA = ops[io];
        const Op opB = ops[(io + 1 < nops) ? io + 1 : io];   // solo tail: dup (benign)

        // B-frags for both ops, issued early
        int4 bfA[8], bfB[8];
        {
            const int4* wA = (const int4*)(wbJ + opA.w);
            const int4* wB = (const int4*)(wbJ + opB.w);
            #pragma unroll
            for (int jt = 0; jt < 4; ++jt)
                #pragma unroll
                for (int kh = 0; kh < 2; ++kh) {
                    bfA[jt*2+kh] = wA[(jt*16 + m) * 8 + kh*4 + q];
                    bfB[jt*2+kh] = wB[(jt*16 + m) * 8 + kh*4 + q];
                }
        }

        float pA[16], pB[16], MrowA, MrowB;
        op_phase<MODE>(opA, xT, Ag, Bg, Cg, inAcc, inM, slotS, Mslot, b0, m, q, pA, MrowA);
        op_phase<MODE>(opB, xT, Ag, Bg, Cg, inAcc, inM, slotS, Mslot, b0, m, q, pB, MrowB);

        bf16x8 aA0, aA1, aB0, aB1;
        pack_p(pA, aA0, aA1);
        pack_p(pB, aB0, aB1);

        f32x4 accA[4], accB[4];
        #pragma unroll
        for (int jt = 0; jt < 4; ++jt) {
            f32x4 zA = {0.f, 0.f, 0.f, 0.f};
            zA = __builtin_amdgcn_mfma_f32_16x16x32_bf16(aA0, *(bf16x8*)&bfA[jt*2+0], zA, 0, 0, 0);
            zA = __builtin_amdgcn_mfma_f32_16x16x32_bf16(aA1, *(bf16x8*)&bfA[jt*2+1], zA, 0, 0, 0);
            accA[jt] = zA;
            f32x4 zB = {0.f, 0.f, 0.f, 0.f};
            zB = __builtin_amdgcn_mfma_f32_16x16x32_bf16(aB0, *(bf16x8*)&bfB[jt*2+0], zB, 0, 0, 0);
            zB = __builtin_amdgcn_mfma_f32_16x16x32_bf16(aB1, *(bf16x8*)&bfB[jt*2+1], zB, 0, 0, 0);
            accB[jt] = zB;
        }

        // ---- epilogues (no log except MODE1 root): C-layout row=4q+r, col=jt*16+m
        #pragma unroll
        for (int which = 0; which < 2; ++which) {
            const Op   op   = which ? opB : opA;
            f32x4*     acc  = which ? accB : accA;
            const float Mr  = which ? MrowB : MrowA;
            const int  d    = (op.meta >> 8) & 15;
            if (d < 15) {
                unsigned short* S = slotS + d * 16 * SROW;
                #pragma unroll
                for (int jt = 0; jt < 4; ++jt)
                    #pragma unroll
                    for (int r = 0; r < 4; ++r)
                        S[(q*4 + r) * SROW + jt*16 + m] = (unsigned short)bfr(acc[jt][r]);
                if (q == 0) Mslot[d * 16 + m] = Mr;
            } else if (MODE == 0) {
                #pragma unroll
                for (int jt = 0; jt < 4; ++jt)
                    #pragma unroll
                    for (int r = 0; r < 4; ++r)
                        outAcc[(size_t)(rowOff + b0 + q*4 + r) * 64 + jt*16 + m] =
                            (unsigned short)bfr(acc[jt][r]);
                if (q == 0) outM[rowOff + b0 + m] = Mr;
            } else {
                float mr[4];
                #pragma unroll
                for (int r = 0; r < 4; ++r) mr[r] = __shfl(Mr, q * 4 + r, 64);
                #pragma unroll
                for (int jt = 0; jt < 4; ++jt)
                    #pragma unroll
                    for (int r = 0; r < 4; ++r)
                        outLog[(b0 + q*4 + r) * 64 + jt*16 + m] =
                            (__builtin_amdgcn_logf(acc[jt][r]) + mr[r]) * LN2_F;
            }
        }
        __builtin_amdgcn_wave_barrier();
        __builtin_amdgcn_s_waitcnt(0xC07F);   // lgkmcnt(0): slot writes visible
        __builtin_amdgcn_wave_barrier();
    }
}

// ---------------------------------------------------------------------------
// d_in order: 0:x 1:mu 2:log_sigma 3:in_scope_idx, then fold_idx{l}, w{l}
// ---------------------------------------------------------------------------
extern "C" void kernel_launch(void* const* d_in, const int* in_sizes, int n_in,
                              void* d_out, int out_size, void* d_ws, size_t ws_size,
                              hipStream_t stream) {
    const float* x     = (const float*)d_in[0];
    const float* mu    = (const float*)d_in[1];
    const float* lsg   = (const float*)d_in[2];
    const int*   scope = (const int*)d_in[3];
    const int*   f1 = (const int*)d_in[4];   const float* w1 = (const float*)d_in[5];
    const int*   f2 = (const int*)d_in[6];   const float* w2 = (const float*)d_in[7];
    const int*   f3 = (const int*)d_in[8];   const float* w3 = (const float*)d_in[9];
    const int*   f4 = (const int*)d_in[10];  const float* w4 = (const float*)d_in[11];
    const int*   f5 = (const int*)d_in[12];  const float* w5 = (const float*)d_in[13];
    const int*   f6 = (const int*)d_in[14];  const float* w6 = (const float*)d_in[15];
    const int*   f7 = (const int*)d_in[16];  const float* w7 = (const float*)d_in[17];
    const int*   f8 = (const int*)d_in[18];  const float* w8 = (const float*)d_in[19];

    char* ws = (char*)d_ws;
    const unsigned short* wbJ = (const unsigned short*)(ws + WS_WBJ);
    const float* Ag  = (const float*)(ws + WS_A);
    const float* Bg  = (const float*)(ws + WS_B);
    const float* Cg  = (const float*)(ws + WS_C);
    const float* xT  = (const float*)(ws + WS_XT);
    const Op*    sch = (const Op*)(ws + WS_SCHED);
    unsigned short* L4A = (unsigned short*)(ws + WS_L4A);
    float*          L4M = (float*)(ws + WS_L4M);

    prep_kernel<<<576, 256, 0, stream>>>(w1, w2, w3, w4, w5, w6, w7, w8,
                                         mu, lsg, x, scope,
                                         f1, f2, f3, f4, f5, f6, f7, f8, ws);

    // levels 1..4: 16 roots x 128 tiles, pair-ILP, no-log chaining
    circuit_x<0><<<2048, 64, 0, stream>>>(
        wbJ, sch, 15, 16,
        xT, Ag, Bg, Cg,
        nullptr, nullptr,
        L4A, L4M, nullptr);

    // levels 5..8: one 15-op tree per batch tile, final natural-log output
    circuit_x<1><<<128, 64, 0, stream>>>(
        wbJ, sch + 240, 15, 1,
        nullptr, nullptr, nullptr, nullptr,
        L4A, L4M,
        nullptr, nullptr, (float*)d_out);
}

// Round 9
// 160.475 us; speedup vs baseline: 1.9640x; 1.0525x over previous
//
#include <hip/hip_runtime.h>
#include <math.h>

#define LOG2PI_F  0.9189385332046727f
#define INV_LN2_F 1.4426950408889634f
#define LN2_F     0.6931471805599453f
#define SROW      72          // slot row stride in shorts (144B, 16B-aligned rows)

typedef short bf16x8 __attribute__((ext_vector_type(8)));
typedef float f32x4  __attribute__((ext_vector_type(4)));

struct __align__(16) Op { int w; int c0; int c1; int pad; };

// ---- workspace byte offsets -------------------------------------------------
#define WS_WBJ   0u          // bf16[255*4096] softmaxed weights, j-major
#define WS_A     2097152u    // float[256*64]  leaf coeff A (log2 domain)
#define WS_B     2162688u    // float[256*64]  leaf coeff B
#define WS_C     2228224u    // float[256*64]  leaf coeff C
#define WS_XT    2293760u    // float[256*2048] x gathered+transposed: xT[d][b]
#define WS_SCHED 4390912u    // Op[16*15 @0 .. K14 trees, 15 @240 .. tail L5-8]
#define WS_L4A   4395008u    // bf16[16*2048*64] level-4 acc values
#define WS_L4M   8589312u    // float[16*2048]   level-4 row scales (log2)

__device__ __forceinline__ short bfr(float f) {   // f32 -> bf16 RNE
    unsigned int u = __float_as_uint(f);
    u += 0x7fffu + ((u >> 16) & 1u);
    return (short)(u >> 16);
}

struct F8v { float v[8]; };
__device__ __forceinline__ F8v ld8(const float* p) {
    F8v r;
    float4 a = *(const float4*)p;
    float4 b = *(const float4*)(p + 4);
    r.v[0]=a.x; r.v[1]=a.y; r.v[2]=a.z; r.v[3]=a.w;
    r.v[4]=b.x; r.v[5]=b.y; r.v[6]=b.z; r.v[7]=b.w;
    return r;
}

__device__ __forceinline__ void up8(int4 v, float* o) {   // 8 bf16 -> f32
    o[0] = __uint_as_float(((unsigned)v.x) << 16);
    o[1] = __uint_as_float(((unsigned)v.x) & 0xffff0000u);
    o[2] = __uint_as_float(((unsigned)v.y) << 16);
    o[3] = __uint_as_float(((unsigned)v.y) & 0xffff0000u);
    o[4] = __uint_as_float(((unsigned)v.z) << 16);
    o[5] = __uint_as_float(((unsigned)v.z) & 0xffff0000u);
    o[6] = __uint_as_float(((unsigned)v.w) << 16);
    o[7] = __uint_as_float(((unsigned)v.w) & 0xffff0000u);
}

__device__ __forceinline__ float rmax16(const float hv[16]) {
    float m01 = fmaxf(hv[0], hv[1]),  m23 = fmaxf(hv[2], hv[3]);
    float m45 = fmaxf(hv[4], hv[5]),  m67 = fmaxf(hv[6], hv[7]);
    float m89 = fmaxf(hv[8], hv[9]),  mab = fmaxf(hv[10], hv[11]);
    float mcd = fmaxf(hv[12], hv[13]), mef = fmaxf(hv[14], hv[15]);
    float hm = fmaxf(fmaxf(fmaxf(m01, m23), fmaxf(m45, m67)),
                     fmaxf(fmaxf(m89, mab), fmaxf(mcd, mef)));
    hm = fmaxf(hm, __shfl_xor(hm, 16, 64));
    hm = fmaxf(hm, __shfl_xor(hm, 32, 64));
    return hm;
}

__device__ __forceinline__ void pack_p(const float e[16], bf16x8& a0, bf16x8& a1) {
    int4 p0, p1;
    p0.x = __builtin_amdgcn_perm(__float_as_uint(e[1]),  __float_as_uint(e[0]),  0x07060302u);
    p0.y = __builtin_amdgcn_perm(__float_as_uint(e[3]),  __float_as_uint(e[2]),  0x07060302u);
    p0.z = __builtin_amdgcn_perm(__float_as_uint(e[5]),  __float_as_uint(e[4]),  0x07060302u);
    p0.w = __builtin_amdgcn_perm(__float_as_uint(e[7]),  __float_as_uint(e[6]),  0x07060302u);
    p1.x = __builtin_amdgcn_perm(__float_as_uint(e[9]),  __float_as_uint(e[8]),  0x07060302u);
    p1.y = __builtin_amdgcn_perm(__float_as_uint(e[11]), __float_as_uint(e[10]), 0x07060302u);
    p1.z = __builtin_amdgcn_perm(__float_as_uint(e[13]), __float_as_uint(e[12]), 0x07060302u);
    p1.w = __builtin_amdgcn_perm(__float_as_uint(e[15]), __float_as_uint(e[14]), 0x07060302u);
    a0 = *(bf16x8*)&p0;
    a1 = *(bf16x8*)&p1;
}

// ---------------------------------------------------------------------------
// Prep: [0,255) softmax->bf16 j-major; [255,319) leaf quadratic coeffs;
// [319,575) x transpose/gather; 575: schedule build — level-DFS order with
// STATIC slots (L1->0..7, L2 j: 2j,2j+1 -> 2j, L3 u: 4u,4u+2 -> 4u, root 0,4).
// ---------------------------------------------------------------------------
__global__ __launch_bounds__(256) void prep_kernel(
    const float* __restrict__ w1, const float* __restrict__ w2,
    const float* __restrict__ w3, const float* __restrict__ w4,
    const float* __restrict__ w5, const float* __restrict__ w6,
    const float* __restrict__ w7, const float* __restrict__ w8,
    const float* __restrict__ mu, const float* __restrict__ ls,
    const float* __restrict__ x,  const int* __restrict__ scope,
    const int* __restrict__ f1, const int* __restrict__ f2,
    const int* __restrict__ f3, const int* __restrict__ f4,
    const int* __restrict__ f5, const int* __restrict__ f6,
    const int* __restrict__ f7, const int* __restrict__ f8,
    char* __restrict__ ws)
{
    const int bx = blockIdx.x, t = threadIdx.x;
    if (bx < 255) {
        __shared__ float smax[64], ssum[64];
        const int g = bx;
        const float* src;
        if (g < 128)      src = w1 + g * 4096;
        else if (g < 192) src = w2 + (g - 128) * 4096;
        else if (g < 224) src = w3 + (g - 192) * 4096;
        else if (g < 240) src = w4 + (g - 224) * 4096;
        else if (g < 248) src = w5 + (g - 240) * 4096;
        else if (g < 252) src = w6 + (g - 248) * 4096;
        else              src = (g < 254) ? (w7 + (g - 252) * 4096) : w8;
        const int lane = t & 63, wv = t >> 6;
        for (int r = 0; r < 16; ++r) {
            int j = wv * 16 + r;
            float v = src[j * 64 + lane];
            float mx = v;
            for (int d = 1; d < 64; d <<= 1) mx = fmaxf(mx, __shfl_xor(mx, d, 64));
            float e = __expf(v - mx);
            float sm = e;
            for (int d = 1; d < 64; d <<= 1) sm += __shfl_xor(sm, d, 64);
            if (lane == 0) { smax[j] = mx; ssum[j] = sm; }
        }
        __syncthreads();
        unsigned short* dst = (unsigned short*)(ws + WS_WBJ) + g * 4096;
        for (int u = 0; u < 16; ++u) {
            int idx = u * 256 + t;
            int j = idx >> 6;
            dst[idx] = (unsigned short)bfr(__expf(src[idx] - smax[j]) / ssum[j]);
        }
    } else if (bx < 319) {
        // h_leaf(d,k)(x) = A x^2 + B x + C  (log2 domain)
        const int idx = (bx - 255) * 256 + t;
        float m = mu[idx], l = ls[idx];
        float is2 = __expf(-2.0f * l);
        ((float*)(ws + WS_A))[idx] = -0.5f * is2 * INV_LN2_F;
        ((float*)(ws + WS_B))[idx] = m * is2 * INV_LN2_F;
        ((float*)(ws + WS_C))[idx] = (-0.5f * m * m * is2 - l - LOG2PI_F) * INV_LN2_F;
    } else if (bx < 575) {
        const int bb = bx - 319;                    // batch range [8bb, 8bb+8)
        const int sd = scope[t];                    // lane t = leaf slot d
        float* xT = (float*)(ws + WS_XT);
        #pragma unroll
        for (int i = 0; i < 8; ++i) {
            int b = bb * 8 + i;
            xT[t * 2048 + b] = x[b * 256 + sd];
        }
    } else {
        // ---- schedule build, folds staged to LDS
        __shared__ int sf[512];
        for (int i = t; i < 256; i += 256) sf[i]        = f1[i];
        for (int i = t; i < 128; i += 256) sf[256 + i]  = f2[i];
        for (int i = t; i <  64; i += 256) sf[384 + i]  = f3[i];
        for (int i = t; i <  32; i += 256) sf[448 + i]  = f4[i];
        for (int i = t; i <  16; i += 256) sf[480 + i]  = f5[i];
        for (int i = t; i <   8; i += 256) sf[496 + i]  = f6[i];
        for (int i = t; i <   4; i += 256) sf[504 + i]  = f7[i];
        for (int i = t; i <   2; i += 256) sf[508 + i]  = f8[i];
        __syncthreads();
        const int* F1 = &sf[0];   const int* F2 = &sf[256];
        const int* F3 = &sf[384]; const int* F4 = &sf[448];
        const int* F5 = &sf[480]; const int* F6 = &sf[496];
        const int* F7 = &sf[504]; const int* F8 = &sf[508];
        Op* base = (Op*)(ws + WS_SCHED);
        if (t < 16) {
            // K14 tree rooted at level-4 node t: 8 leaves (DFS), 4 L2, 2 L3, root
            Op* o = base + t * 15;
            int r0 = F4[2*t], r1 = F4[2*t+1];
            int P[4] = { F3[2*r0], F3[2*r0+1], F3[2*r1], F3[2*r1+1] };
            #pragma unroll
            for (int j = 0; j < 4; ++j) {
                int L0 = F2[2*P[j]], L1 = F2[2*P[j]+1];
                o[2*j]   = { L0 * 4096, F1[2*L0], F1[2*L0+1], 0 };
                o[2*j+1] = { L1 * 4096, F1[2*L1], F1[2*L1+1], 0 };
                o[8+j]   = { (128 + P[j]) * 4096, 0, 0, 0 };
            }
            o[12] = { (192 + r0) * 4096, 0, 0, 0 };
            o[13] = { (192 + r1) * 4096, 0, 0, 0 };
            o[14] = { (224 + t)  * 4096, 0, 0, 0 };
        } else if (t == 16) {
            // Tail tree, levels 5..8, same static-slot level-DFS layout
            Op* o = base + 240;
            int g[4] = { F7[2*F8[0]], F7[2*F8[0]+1], F7[2*F8[1]], F7[2*F8[1]+1] };
            #pragma unroll
            for (int a = 0; a < 4; ++a) {
                int l0 = F6[2*g[a]], l1 = F6[2*g[a]+1];     // L5 node ids
                o[2*a]   = { (240 + l0) * 4096, F5[2*l0], F5[2*l0+1], 0 };
                o[2*a+1] = { (240 + l1) * 4096, F5[2*l1], F5[2*l1+1], 0 };
                o[8+a]   = { (248 + g[a]) * 4096, 0, 0, 0 };
            }
            o[12] = { (252 + F8[0]) * 4096, 0, 0, 0 };
            o[13] = { (252 + F8[1]) * 4096, 0, 0, 0 };
            o[14] = { 254 * 4096, 0, 0, 0 };
        }
    }
}

// ---------------------------------------------------------------------------
// Per-op helpers (all values linear-domain with per-row pow2 scale M)
// ---------------------------------------------------------------------------
__device__ __forceinline__ void load_bfrag(const unsigned short* __restrict__ wbJ,
                                           int w, int m, int q, int4 bf[8]) {
    const int4* wp = (const int4*)(wbJ + w);
    #pragma unroll
    for (int jt = 0; jt < 4; ++jt)
        #pragma unroll
        for (int kh = 0; kh < 2; ++kh)
            bf[jt*2+kh] = wp[(jt*16 + m) * 8 + kh*4 + q];
}

__device__ __forceinline__ void prod_norm(const float av[16], const float bv[16],
                                          float MA, float MB,
                                          float p[16], float& Mrow) {
    float pv[16];
    #pragma unroll
    for (int i = 0; i < 16; ++i) pv[i] = av[i] * bv[i];
    const float rm = rmax16(pv);
    const int e = (int)((__float_as_uint(rm) >> 23) & 0xFF) - 127;
    #pragma unroll
    for (int i = 0; i < 16; ++i) p[i] = ldexpf(pv[i], -e);   // exact scaling
    Mrow = MA + MB + (float)e;
}

__device__ __forceinline__ void gauss_p(const Op& op,
    const float* __restrict__ xT, const float* __restrict__ Ag,
    const float* __restrict__ Bg, const float* __restrict__ Cg,
    int b0, int m, int q, float p[16], float& Mrow)
{
    const int d0 = op.c0, d1 = op.c1;
    const float xv0 = xT[d0 * 2048 + b0 + m];
    const float xv1 = xT[d1 * 2048 + b0 + m];
    const float x0s = xv0 * xv0, x1s = xv1 * xv1;
    float hv[16];
    #pragma unroll
    for (int kh = 0; kh < 2; ++kh) {
        const int kb = kh * 32 + q * 8;
        F8v A0 = ld8(Ag + d0*64 + kb), B0 = ld8(Bg + d0*64 + kb);
        F8v C0 = ld8(Cg + d0*64 + kb);
        F8v A1 = ld8(Ag + d1*64 + kb), B1 = ld8(Bg + d1*64 + kb);
        F8v C1 = ld8(Cg + d1*64 + kb);
        #pragma unroll
        for (int i = 0; i < 8; ++i) {
            float t0 = fmaf(A0.v[i], x0s, C0.v[i]);
            t0 = fmaf(B0.v[i], xv0, t0);
            float t1 = fmaf(A1.v[i], x1s, C1.v[i]);
            t1 = fmaf(B1.v[i], xv1, t1);
            hv[kh*8+i] = t0 + t1;
        }
    }
    const float hm = rmax16(hv);
    #pragma unroll
    for (int i = 0; i < 16; ++i) p[i] = __builtin_amdgcn_exp2f(hv[i] - hm);
    Mrow = hm;
}

__device__ __forceinline__ void gprod_p(const Op& op,
    const unsigned short* __restrict__ inAcc, const float* __restrict__ inM,
    int b0, int m, int q, float p[16], float& Mrow)
{
    const int4* A4 = (const int4*)(inAcc + (size_t)(op.c0 * 2048 + b0 + m) * 64);
    const int4* B4 = (const int4*)(inAcc + (size_t)(op.c1 * 2048 + b0 + m) * 64);
    float av[16], bv[16];
    up8(A4[q], av); up8(A4[4+q], av + 8);
    up8(B4[q], bv); up8(B4[4+q], bv + 8);
    prod_norm(av, bv, inM[op.c0 * 2048 + b0 + m], inM[op.c1 * 2048 + b0 + m], p, Mrow);
}

__device__ __forceinline__ void slot_prod(const unsigned short* slotS, const float* Mslot,
                                          int sA, int sB, int m, int q,
                                          float p[16], float& Mrow)
{
    const int4* A4 = (const int4*)(slotS + sA * 16 * SROW + m * SROW);
    const int4* B4 = (const int4*)(slotS + sB * 16 * SROW + m * SROW);
    float av[16], bv[16];
    up8(A4[q], av); up8(A4[4+q], av + 8);
    up8(B4[q], bv); up8(B4[4+q], bv + 8);
    prod_norm(av, bv, Mslot[sA * 16 + m], Mslot[sB * 16 + m], p, Mrow);
}

__device__ __forceinline__ void mfma8(const float p[16], const int4 bf[8], f32x4 acc[4]) {
    bf16x8 a0, a1;
    pack_p(p, a0, a1);
    #pragma unroll
    for (int jt = 0; jt < 4; ++jt) {
        f32x4 z = {0.f, 0.f, 0.f, 0.f};
        z = __builtin_amdgcn_mfma_f32_16x16x32_bf16(a0, *(bf16x8*)&bf[jt*2+0], z, 0, 0, 0);
        z = __builtin_amdgcn_mfma_f32_16x16x32_bf16(a1, *(bf16x8*)&bf[jt*2+1], z, 0, 0, 0);
        acc[jt] = z;
    }
}

__device__ __forceinline__ void store_slot(unsigned short* slotS, float* Mslot,
                                           int sl, const f32x4 acc[4], float Mrow,
                                           int m, int q)
{
    unsigned short* S = slotS + sl * 16 * SROW;
    #pragma unroll
    for (int jt = 0; jt < 4; ++jt)
        #pragma unroll
        for (int r = 0; r < 4; ++r)
            S[(q*4 + r) * SROW + jt*16 + m] = (unsigned short)bfr(acc[jt][r]);
    if (q == 0) Mslot[sl * 16 + m] = Mrow;
}

__device__ __forceinline__ void wave_fence() {
    __builtin_amdgcn_wave_barrier();
    __builtin_amdgcn_s_waitcnt(0xC07F);   // lgkmcnt(0)
    __builtin_amdgcn_wave_barrier();
}

// ---------------------------------------------------------------------------
// Cooperative 2-wave tree kernel. Block = 128 threads = 2 waves, 16-row tile.
// Static DFS slot layout makes each wave's half-tree self-contained:
//   wave wv: leaves -> slots 4wv..4wv+3; L2 -> 4wv, 4wv+2; L3 -> 4wv.
// Only the root (wave 0, reads slots 0 & 4) crosses waves -> ONE __syncthreads.
// MODE 0: K14 (Gauss leaves, root -> L4 acc+M). MODE 1: tail L5-8 (global-
// product leaves, root -> d_out natural log).
// ---------------------------------------------------------------------------
template<int MODE>
__global__ __launch_bounds__(128, 4) void circuit_coop(
    const unsigned short* __restrict__ wbJ,
    const Op* __restrict__ schedG, int nsub,
    const float* __restrict__ xT, const float* __restrict__ Ag,
    const float* __restrict__ Bg, const float* __restrict__ Cg,
    const unsigned short* __restrict__ inAcc, const float* __restrict__ inM,
    unsigned short* __restrict__ outAcc, float* __restrict__ outM,
    float* __restrict__ outLog)
{
    __shared__ __align__(16) unsigned short slotS[8 * 16 * SROW];  // 18.4 KB
    __shared__ float Mslot[8 * 16];
    __shared__ Op ops[16];

    const int t    = threadIdx.x;
    const int wv   = t >> 6;
    const int lane = t & 63;
    const int m    = lane & 15;
    const int q    = lane >> 4;
    const int s    = blockIdx.x % nsub;
    const int b0   = (blockIdx.x / nsub) * 16;

    if (t < 15) *(int4*)&ops[t] = ((const int4*)(schedG + s * 15))[t];
    __syncthreads();

    // ---- phase 1: 4 leaves per wave -> slots 4wv+i
    #pragma unroll 1
    for (int i = 0; i < 4; ++i) {
        const int sl = 4 * wv + i;
        const Op op = ops[sl];
        int4 bf[8];
        load_bfrag(wbJ, op.w, m, q, bf);
        float p[16], Mrow;
        if (MODE == 0) gauss_p(op, xT, Ag, Bg, Cg, b0, m, q, p, Mrow);
        else           gprod_p(op, inAcc, inM, b0, m, q, p, Mrow);
        f32x4 acc[4];
        mfma8(p, bf, acc);
        store_slot(slotS, Mslot, sl, acc, Mrow, m, q);
    }
    wave_fence();

    // ---- phase 2: 2 L2-mixes per wave: j = 2wv+i reads 2j,2j+1 -> 2j
    #pragma unroll 1
    for (int i = 0; i < 2; ++i) {
        const int j = 2 * wv + i;
        const Op op = ops[8 + j];
        int4 bf[8];
        load_bfrag(wbJ, op.w, m, q, bf);
        float p[16], Mrow;
        slot_prod(slotS, Mslot, 2*j, 2*j + 1, m, q, p, Mrow);
        f32x4 acc[4];
        mfma8(p, bf, acc);
        store_slot(slotS, Mslot, 2*j, acc, Mrow, m, q);
    }
    wave_fence();

    // ---- phase 3: 1 L3-mix per wave: u = wv reads 4u,4u+2 -> 4u
    {
        const Op op = ops[12 + wv];
        int4 bf[8];
        load_bfrag(wbJ, op.w, m, q, bf);
        float p[16], Mrow;
        slot_prod(slotS, Mslot, 4*wv, 4*wv + 2, m, q, p, Mrow);
        f32x4 acc[4];
        mfma8(p, bf, acc);
        store_slot(slotS, Mslot, 4*wv, acc, Mrow, m, q);
    }
    __syncthreads();   // the only cross-wave handoff: root reads slots 0 and 4

    // ---- phase 4: root (wave 0)
    if (wv == 0) {
        const Op op = ops[14];
        int4 bf[8];
        load_bfrag(wbJ, op.w, m, q, bf);
        float p[16], Mrow;
        slot_prod(slotS, Mslot, 0, 4, m, q, p, Mrow);
        f32x4 acc[4];
        mfma8(p, bf, acc);
        if (MODE == 0) {
            const int rowOff = s * 2048;
            #pragma unroll
            for (int jt = 0; jt < 4; ++jt)
                #pragma unroll
                for (int r = 0; r < 4; ++r)
                    outAcc[(size_t)(rowOff + b0 + q*4 + r) * 64 + jt*16 + m] =
                        (unsigned short)bfr(acc[jt][r]);
            if (q == 0) outM[rowOff + b0 + m] = Mrow;
        } else {
            float mr[4];
            #pragma unroll
            for (int r = 0; r < 4; ++r) mr[r] = __shfl(Mrow, q * 4 + r, 64);
            #pragma unroll
            for (int jt = 0; jt < 4; ++jt)
                #pragma unroll
                for (int r = 0; r < 4; ++r)
                    outLog[(b0 + q*4 + r) * 64 + jt*16 + m] =
                        (__builtin_amdgcn_logf(acc[jt][r]) + mr[r]) * LN2_F;
        }
    }
}

// ---------------------------------------------------------------------------
// d_in order: 0:x 1:mu 2:log_sigma 3:in_scope_idx, then fold_idx{l}, w{l}
// ---------------------------------------------------------------------------
extern "C" void kernel_launch(void* const* d_in, const int* in_sizes, int n_in,
                              void* d_out, int out_size, void* d_ws, size_t ws_size,
                              hipStream_t stream) {
    const float* x     = (const float*)d_in[0];
    const float* mu    = (const float*)d_in[1];
    const float* lsg   = (const float*)d_in[2];
    const int*   scope = (const int*)d_in[3];
    const int*   f1 = (const int*)d_in[4];   const float* w1 = (const float*)d_in[5];
    const int*   f2 = (const int*)d_in[6];   const float* w2 = (const float*)d_in[7];
    const int*   f3 = (const int*)d_in[8];   const float* w3 = (const float*)d_in[9];
    const int*   f4 = (const int*)d_in[10];  const float* w4 = (const float*)d_in[11];
    const int*   f5 = (const int*)d_in[12];  const float* w5 = (const float*)d_in[13];
    const int*   f6 = (const int*)d_in[14];  const float* w6 = (const float*)d_in[15];
    const int*   f7 = (const int*)d_in[16];  const float* w7 = (const float*)d_in[17];
    const int*   f8 = (const int*)d_in[18];  const float* w8 = (const float*)d_in[19];

    char* ws = (char*)d_ws;
    const unsigned short* wbJ = (const unsigned short*)(ws + WS_WBJ);
    const float* Ag  = (const float*)(ws + WS_A);
    const float* Bg  = (const float*)(ws + WS_B);
    const float* Cg  = (const float*)(ws + WS_C);
    const float* xT  = (const float*)(ws + WS_XT);
    const Op*    sch = (const Op*)(ws + WS_SCHED);
    unsigned short* L4A = (unsigned short*)(ws + WS_L4A);
    float*          L4M = (float*)(ws + WS_L4M);

    prep_kernel<<<576, 256, 0, stream>>>(w1, w2, w3, w4, w5, w6, w7, w8,
                                         mu, lsg, x, scope,
                                         f1, f2, f3, f4, f5, f6, f7, f8, ws);

    // levels 1..4: 16 roots x 128 tiles, 2-wave cooperative trees
    circuit_coop<0><<<2048, 128, 0, stream>>>(
        wbJ, sch, 16,
        xT, Ag, Bg, Cg,
        nullptr, nullptr,
        L4A, L4M, nullptr);

    // levels 5..8: one tree per batch tile, final natural-log output
    circuit_coop<1><<<128, 128, 0, stream>>>(
        wbJ, sch + 240, 1,
        nullptr, nullptr, nullptr, nullptr,
        L4A, L4M,
        nullptr, nullptr, (float*)d_out);
}

// Round 10
// 145.741 us; speedup vs baseline: 2.1626x; 1.1011x over previous
//
#include <hip/hip_runtime.h>
#include <math.h>

#define LOG2PI_F  0.9189385332046727f
#define INV_LN2_F 1.4426950408889634f
#define LN2_F     0.6931471805599453f
#define SROW      72          // slot row stride in shorts (144B, 16B-aligned rows)

typedef short bf16x8 __attribute__((ext_vector_type(8)));
typedef float f32x4  __attribute__((ext_vector_type(4)));

struct __align__(16) Op { int w; int c0; int c1; int pad; };

// ---- workspace byte offsets -------------------------------------------------
#define WS_WBJ   0u          // bf16[255][8 frag][64 lane][8] pre-swizzled weights
#define WS_A     2097152u    // float[256*64]  leaf coeff A (log2 domain)
#define WS_B     2162688u    // float[256*64]  leaf coeff B
#define WS_C     2228224u    // float[256*64]  leaf coeff C
#define WS_XT    2293760u    // float[256*2048] x gathered+transposed: xT[d][b]
#define WS_SCHED 4390912u    // Op[16*15 @0 .. K14 trees, 15 @240 .. tail L5-8]
#define WS_L4A   4395008u    // bf16[16*2048*64] level-4 acc values
#define WS_L4M   8589312u    // float[16*2048]   level-4 row scales (log2)

__device__ __forceinline__ short bfr(float f) {   // f32 -> bf16 RNE
    unsigned int u = __float_as_uint(f);
    u += 0x7fffu + ((u >> 16) & 1u);
    return (short)(u >> 16);
}

struct F8v { float v[8]; };
__device__ __forceinline__ F8v ld8(const float* p) {
    F8v r;
    float4 a = *(const float4*)p;
    float4 b = *(const float4*)(p + 4);
    r.v[0]=a.x; r.v[1]=a.y; r.v[2]=a.z; r.v[3]=a.w;
    r.v[4]=b.x; r.v[5]=b.y; r.v[6]=b.z; r.v[7]=b.w;
    return r;
}

__device__ __forceinline__ void up8(int4 v, float* o) {   // 8 bf16 -> f32
    o[0] = __uint_as_float(((unsigned)v.x) << 16);
    o[1] = __uint_as_float(((unsigned)v.x) & 0xffff0000u);
    o[2] = __uint_as_float(((unsigned)v.y) << 16);
    o[3] = __uint_as_float(((unsigned)v.y) & 0xffff0000u);
    o[4] = __uint_as_float(((unsigned)v.z) << 16);
    o[5] = __uint_as_float(((unsigned)v.z) & 0xffff0000u);
    o[6] = __uint_as_float(((unsigned)v.w) << 16);
    o[7] = __uint_as_float(((unsigned)v.w) & 0xffff0000u);
}

__device__ __forceinline__ float rmax16(const float hv[16]) {
    float m01 = fmaxf(hv[0], hv[1]),  m23 = fmaxf(hv[2], hv[3]);
    float m45 = fmaxf(hv[4], hv[5]),  m67 = fmaxf(hv[6], hv[7]);
    float m89 = fmaxf(hv[8], hv[9]),  mab = fmaxf(hv[10], hv[11]);
    float mcd = fmaxf(hv[12], hv[13]), mef = fmaxf(hv[14], hv[15]);
    float hm = fmaxf(fmaxf(fmaxf(m01, m23), fmaxf(m45, m67)),
                     fmaxf(fmaxf(m89, mab), fmaxf(mcd, mef)));
    hm = fmaxf(hm, __shfl_xor(hm, 16, 64));
    hm = fmaxf(hm, __shfl_xor(hm, 32, 64));
    return hm;
}

__device__ __forceinline__ void pack_p(const float e[16], bf16x8& a0, bf16x8& a1) {
    int4 p0, p1;
    p0.x = __builtin_amdgcn_perm(__float_as_uint(e[1]),  __float_as_uint(e[0]),  0x07060302u);
    p0.y = __builtin_amdgcn_perm(__float_as_uint(e[3]),  __float_as_uint(e[2]),  0x07060302u);
    p0.z = __builtin_amdgcn_perm(__float_as_uint(e[5]),  __float_as_uint(e[4]),  0x07060302u);
    p0.w = __builtin_amdgcn_perm(__float_as_uint(e[7]),  __float_as_uint(e[6]),  0x07060302u);
    p1.x = __builtin_amdgcn_perm(__float_as_uint(e[9]),  __float_as_uint(e[8]),  0x07060302u);
    p1.y = __builtin_amdgcn_perm(__float_as_uint(e[11]), __float_as_uint(e[10]), 0x07060302u);
    p1.z = __builtin_amdgcn_perm(__float_as_uint(e[13]), __float_as_uint(e[12]), 0x07060302u);
    p1.w = __builtin_amdgcn_perm(__float_as_uint(e[15]), __float_as_uint(e[14]), 0x07060302u);
    a0 = *(bf16x8*)&p0;
    a1 = *(bf16x8*)&p1;
}

// ---------------------------------------------------------------------------
// Prep: [0,255) softmax -> bf16 FRAG-SWIZZLED layout (each B-frag load in the
// circuit kernel becomes one fully-coalesced 1KB read); [255,319) leaf coeffs;
// [319,575) x transpose/gather; 575: schedule build.
// Swizzle: element (j,k) -> frag f=(j>>4)*2+(k>>5), lane=((k>>3)&3)*16+(j&15),
//          pos=k&7; dst[(f*64+lane)*8+pos].
// ---------------------------------------------------------------------------
__global__ __launch_bounds__(256) void prep_kernel(
    const float* __restrict__ w1, const float* __restrict__ w2,
    const float* __restrict__ w3, const float* __restrict__ w4,
    const float* __restrict__ w5, const float* __restrict__ w6,
    const float* __restrict__ w7, const float* __restrict__ w8,
    const float* __restrict__ mu, const float* __restrict__ ls,
    const float* __restrict__ x,  const int* __restrict__ scope,
    const int* __restrict__ f1, const int* __restrict__ f2,
    const int* __restrict__ f3, const int* __restrict__ f4,
    const int* __restrict__ f5, const int* __restrict__ f6,
    const int* __restrict__ f7, const int* __restrict__ f8,
    char* __restrict__ ws)
{
    const int bx = blockIdx.x, t = threadIdx.x;
    if (bx < 255) {
        __shared__ float smax[64], ssum[64];
        const int g = bx;
        const float* src;
        if (g < 128)      src = w1 + g * 4096;
        else if (g < 192) src = w2 + (g - 128) * 4096;
        else if (g < 224) src = w3 + (g - 192) * 4096;
        else if (g < 240) src = w4 + (g - 224) * 4096;
        else if (g < 248) src = w5 + (g - 240) * 4096;
        else if (g < 252) src = w6 + (g - 248) * 4096;
        else              src = (g < 254) ? (w7 + (g - 252) * 4096) : w8;
        const int lane = t & 63, wv = t >> 6;
        for (int r = 0; r < 16; ++r) {
            int j = wv * 16 + r;
            float v = src[j * 64 + lane];
            float mx = v;
            for (int d = 1; d < 64; d <<= 1) mx = fmaxf(mx, __shfl_xor(mx, d, 64));
            float e = __expf(v - mx);
            float sm = e;
            for (int d = 1; d < 64; d <<= 1) sm += __shfl_xor(sm, d, 64);
            if (lane == 0) { smax[j] = mx; ssum[j] = sm; }
        }
        __syncthreads();
        unsigned short* dst = (unsigned short*)(ws + WS_WBJ) + g * 4096;
        for (int u = 0; u < 16; ++u) {
            int idx = u * 256 + t;
            int j = idx >> 6, k = idx & 63;
            float v = __expf(src[idx] - smax[j]) / ssum[j];
            int f  = ((j >> 4) << 1) | (k >> 5);
            int ln = (((k >> 3) & 3) << 4) | (j & 15);
            dst[(f * 64 + ln) * 8 + (k & 7)] = (unsigned short)bfr(v);
        }
    } else if (bx < 319) {
        // h_leaf(d,k)(x) = A x^2 + B x + C  (log2 domain)
        const int idx = (bx - 255) * 256 + t;
        float m = mu[idx], l = ls[idx];
        float is2 = __expf(-2.0f * l);
        ((float*)(ws + WS_A))[idx] = -0.5f * is2 * INV_LN2_F;
        ((float*)(ws + WS_B))[idx] = m * is2 * INV_LN2_F;
        ((float*)(ws + WS_C))[idx] = (-0.5f * m * m * is2 - l - LOG2PI_F) * INV_LN2_F;
    } else if (bx < 575) {
        const int bb = bx - 319;                    // batch range [8bb, 8bb+8)
        const int sd = scope[t];                    // lane t = leaf slot d
        float* xT = (float*)(ws + WS_XT);
        #pragma unroll
        for (int i = 0; i < 8; ++i) {
            int b = bb * 8 + i;
            xT[t * 2048 + b] = x[b * 256 + sd];
        }
    } else {
        // ---- schedule build, folds staged to LDS
        __shared__ int sf[512];
        for (int i = t; i < 256; i += 256) sf[i]        = f1[i];
        for (int i = t; i < 128; i += 256) sf[256 + i]  = f2[i];
        for (int i = t; i <  64; i += 256) sf[384 + i]  = f3[i];
        for (int i = t; i <  32; i += 256) sf[448 + i]  = f4[i];
        for (int i = t; i <  16; i += 256) sf[480 + i]  = f5[i];
        for (int i = t; i <   8; i += 256) sf[496 + i]  = f6[i];
        for (int i = t; i <   4; i += 256) sf[504 + i]  = f7[i];
        for (int i = t; i <   2; i += 256) sf[508 + i]  = f8[i];
        __syncthreads();
        const int* F1 = &sf[0];   const int* F2 = &sf[256];
        const int* F3 = &sf[384]; const int* F4 = &sf[448];
        const int* F5 = &sf[480]; const int* F6 = &sf[496];
        const int* F7 = &sf[504]; const int* F8 = &sf[508];
        Op* base = (Op*)(ws + WS_SCHED);
        if (t < 16) {
            // K14 tree rooted at level-4 node t: 8 leaves (DFS), 4 L2, 2 L3, root
            Op* o = base + t * 15;
            int r0 = F4[2*t], r1 = F4[2*t+1];
            int P[4] = { F3[2*r0], F3[2*r0+1], F3[2*r1], F3[2*r1+1] };
            #pragma unroll
            for (int j = 0; j < 4; ++j) {
                int L0 = F2[2*P[j]], L1 = F2[2*P[j]+1];
                o[2*j]   = { L0 * 4096, F1[2*L0], F1[2*L0+1], 0 };
                o[2*j+1] = { L1 * 4096, F1[2*L1], F1[2*L1+1], 0 };
                o[8+j]   = { (128 + P[j]) * 4096, 0, 0, 0 };
            }
            o[12] = { (192 + r0) * 4096, 0, 0, 0 };
            o[13] = { (192 + r1) * 4096, 0, 0, 0 };
            o[14] = { (224 + t)  * 4096, 0, 0, 0 };
        } else if (t == 16) {
            // Tail tree, levels 5..8, same static-slot level-DFS layout
            Op* o = base + 240;
            int g[4] = { F7[2*F8[0]], F7[2*F8[0]+1], F7[2*F8[1]], F7[2*F8[1]+1] };
            #pragma unroll
            for (int a = 0; a < 4; ++a) {
                int l0 = F6[2*g[a]], l1 = F6[2*g[a]+1];     // L5 node ids
                o[2*a]   = { (240 + l0) * 4096, F5[2*l0], F5[2*l0+1], 0 };
                o[2*a+1] = { (240 + l1) * 4096, F5[2*l1], F5[2*l1+1], 0 };
                o[8+a]   = { (248 + g[a]) * 4096, 0, 0, 0 };
            }
            o[12] = { (252 + F8[0]) * 4096, 0, 0, 0 };
            o[13] = { (252 + F8[1]) * 4096, 0, 0, 0 };
            o[14] = { 254 * 4096, 0, 0, 0 };
        }
    }
}

// ---------------------------------------------------------------------------
// Per-op helpers (linear-domain values with per-row pow2 scale M)
// ---------------------------------------------------------------------------
__device__ __forceinline__ void load_bfrag(const unsigned short* __restrict__ wbJ,
                                           int w, int lane, int4 bf[8]) {
    const int4* wp = (const int4*)(wbJ + w);
    #pragma unroll
    for (int f = 0; f < 8; ++f) bf[f] = wp[f * 64 + lane];   // coalesced 1KB/load
}

__device__ __forceinline__ void prod_norm(const float av[16], const float bv[16],
                                          float MA, float MB,
                                          float p[16], float& Mrow) {
    float pv[16];
    #pragma unroll
    for (int i = 0; i < 16; ++i) pv[i] = av[i] * bv[i];
    const float rm = rmax16(pv);
    const int e = (int)((__float_as_uint(rm) >> 23) & 0xFF) - 127;
    #pragma unroll
    for (int i = 0; i < 16; ++i) p[i] = ldexpf(pv[i], -e);   // exact scaling
    Mrow = MA + MB + (float)e;
}

__device__ __forceinline__ void gauss_p(const Op& op,
    const float* __restrict__ xT, const float* __restrict__ Ag,
    const float* __restrict__ Bg, const float* __restrict__ Cg,
    int b0, int m, int q, float p[16], float& Mrow)
{
    const int d0 = op.c0, d1 = op.c1;
    const float xv0 = xT[d0 * 2048 + b0 + m];
    const float xv1 = xT[d1 * 2048 + b0 + m];
    const float x0s = xv0 * xv0, x1s = xv1 * xv1;
    float hv[16];
    #pragma unroll
    for (int kh = 0; kh < 2; ++kh) {
        const int kb = kh * 32 + q * 8;
        F8v A0 = ld8(Ag + d0*64 + kb), B0 = ld8(Bg + d0*64 + kb);
        F8v C0 = ld8(Cg + d0*64 + kb);
        F8v A1 = ld8(Ag + d1*64 + kb), B1 = ld8(Bg + d1*64 + kb);
        F8v C1 = ld8(Cg + d1*64 + kb);
        #pragma unroll
        for (int i = 0; i < 8; ++i) {
            float t0 = fmaf(A0.v[i], x0s, C0.v[i]);
            t0 = fmaf(B0.v[i], xv0, t0);
            float t1 = fmaf(A1.v[i], x1s, C1.v[i]);
            t1 = fmaf(B1.v[i], xv1, t1);
            hv[kh*8+i] = t0 + t1;
        }
    }
    const float hm = rmax16(hv);
    #pragma unroll
    for (int i = 0; i < 16; ++i) p[i] = __builtin_amdgcn_exp2f(hv[i] - hm);
    Mrow = hm;
}

__device__ __forceinline__ void gprod_p(const Op& op,
    const unsigned short* __restrict__ inAcc, const float* __restrict__ inM,
    int b0, int m, int q, float p[16], float& Mrow)
{
    const int4* A4 = (const int4*)(inAcc + (size_t)(op.c0 * 2048 + b0 + m) * 64);
    const int4* B4 = (const int4*)(inAcc + (size_t)(op.c1 * 2048 + b0 + m) * 64);
    float av[16], bv[16];
    up8(A4[q], av); up8(A4[4+q], av + 8);
    up8(B4[q], bv); up8(B4[4+q], bv + 8);
    prod_norm(av, bv, inM[op.c0 * 2048 + b0 + m], inM[op.c1 * 2048 + b0 + m], p, Mrow);
}

__device__ __forceinline__ void slot_prod(const unsigned short* slotS, const float* Mslot,
                                          int sA, int sB, int m, int q,
                                          float p[16], float& Mrow)
{
    const int4* A4 = (const int4*)(slotS + sA * 16 * SROW + m * SROW);
    const int4* B4 = (const int4*)(slotS + sB * 16 * SROW + m * SROW);
    float av[16], bv[16];
    up8(A4[q], av); up8(A4[4+q], av + 8);
    up8(B4[q], bv); up8(B4[4+q], bv + 8);
    prod_norm(av, bv, Mslot[sA * 16 + m], Mslot[sB * 16 + m], p, Mrow);
}

__device__ __forceinline__ void mfma8(const float p[16], const int4 bf[8], f32x4 acc[4]) {
    bf16x8 a0, a1;
    pack_p(p, a0, a1);
    #pragma unroll
    for (int jt = 0; jt < 4; ++jt) {
        f32x4 z = {0.f, 0.f, 0.f, 0.f};
        z = __builtin_amdgcn_mfma_f32_16x16x32_bf16(a0, *(bf16x8*)&bf[jt*2+0], z, 0, 0, 0);
        z = __builtin_amdgcn_mfma_f32_16x16x32_bf16(a1, *(bf16x8*)&bf[jt*2+1], z, 0, 0, 0);
        acc[jt] = z;
    }
}

__device__ __forceinline__ void store_slot(unsigned short* slotS, float* Mslot,
                                           int sl, const f32x4 acc[4], float Mrow,
                                           int m, int q)
{
    unsigned short* S = slotS + sl * 16 * SROW;
    #pragma unroll
    for (int jt = 0; jt < 4; ++jt)
        #pragma unroll
        for (int r = 0; r < 4; ++r)
            S[(q*4 + r) * SROW + jt*16 + m] = (unsigned short)bfr(acc[jt][r]);
    if (q == 0) Mslot[sl * 16 + m] = Mrow;
}

__device__ __forceinline__ void wave_fence() {
    __builtin_amdgcn_wave_barrier();
    __builtin_amdgcn_s_waitcnt(0xC07F);   // lgkmcnt(0)
    __builtin_amdgcn_wave_barrier();
}

// ---------------------------------------------------------------------------
// Cooperative 2-wave tree kernel with explicit pair-ILP inside each phase.
// Block = 128 threads = 2 waves, 16-row tile. Static DFS slot layout keeps
// each wave's half-tree self-contained; only the root crosses waves.
// MODE 0: K14 (Gauss leaves, root -> L4 acc+M). MODE 1: tail L5-8.
// ---------------------------------------------------------------------------
template<int MODE>
__global__ __launch_bounds__(128, 4) void circuit_coop(
    const unsigned short* __restrict__ wbJ,
    const Op* __restrict__ schedG, int nsub,
    const float* __restrict__ xT, const float* __restrict__ Ag,
    const float* __restrict__ Bg, const float* __restrict__ Cg,
    const unsigned short* __restrict__ inAcc, const float* __restrict__ inM,
    unsigned short* __restrict__ outAcc, float* __restrict__ outM,
    float* __restrict__ outLog)
{
    __shared__ __align__(16) unsigned short slotS[8 * 16 * SROW];  // 18.4 KB
    __shared__ float Mslot[8 * 16];
    __shared__ Op ops[16];

    const int t    = threadIdx.x;
    const int wv   = t >> 6;
    const int lane = t & 63;
    const int m    = lane & 15;
    const int q    = lane >> 4;
    const int s    = blockIdx.x % nsub;
    const int b0   = (blockIdx.x / nsub) * 16;

    if (t < 15) *(int4*)&ops[t] = ((const int4*)(schedG + s * 15))[t];
    __syncthreads();

    // ---- phase 1: 4 leaves per wave, two independent PAIRS
    #pragma unroll
    for (int pr = 0; pr < 2; ++pr) {
        const int slA = 4 * wv + 2 * pr;
        const int slB = slA + 1;
        const Op opA = ops[slA], opB = ops[slB];
        int4 bfA[8], bfB[8];
        load_bfrag(wbJ, opA.w, lane, bfA);
        load_bfrag(wbJ, opB.w, lane, bfB);
        float pA[16], pB[16], MA, MB;
        if (MODE == 0) {
            gauss_p(opA, xT, Ag, Bg, Cg, b0, m, q, pA, MA);
            gauss_p(opB, xT, Ag, Bg, Cg, b0, m, q, pB, MB);
        } else {
            gprod_p(opA, inAcc, inM, b0, m, q, pA, MA);
            gprod_p(opB, inAcc, inM, b0, m, q, pB, MB);
        }
        f32x4 accA[4], accB[4];
        mfma8(pA, bfA, accA);
        mfma8(pB, bfB, accB);
        store_slot(slotS, Mslot, slA, accA, MA, m, q);
        store_slot(slotS, Mslot, slB, accB, MB, m, q);
    }
    wave_fence();

    // ---- phase 2: 2 L2-mixes per wave as one PAIR: j=2wv+i reads 2j,2j+1 -> 2j
    {
        const int jA = 2 * wv, jB = 2 * wv + 1;
        const Op opA = ops[8 + jA], opB = ops[8 + jB];
        int4 bfA[8], bfB[8];
        load_bfrag(wbJ, opA.w, lane, bfA);
        load_bfrag(wbJ, opB.w, lane, bfB);
        float pA[16], pB[16], MA, MB;
        slot_prod(slotS, Mslot, 2*jA, 2*jA + 1, m, q, pA, MA);
        slot_prod(slotS, Mslot, 2*jB, 2*jB + 1, m, q, pB, MB);
        f32x4 accA[4], accB[4];
        mfma8(pA, bfA, accA);
        mfma8(pB, bfB, accB);
        store_slot(slotS, Mslot, 2*jA, accA, MA, m, q);
        store_slot(slotS, Mslot, 2*jB, accB, MB, m, q);
    }
    wave_fence();

    // ---- phase 3: 1 L3-mix per wave: u = wv reads 4u,4u+2 -> 4u
    {
        const Op op = ops[12 + wv];
        int4 bf[8];
        load_bfrag(wbJ, op.w, lane, bf);
        float p[16], Mrow;
        slot_prod(slotS, Mslot, 4*wv, 4*wv + 2, m, q, p, Mrow);
        f32x4 acc[4];
        mfma8(p, bf, acc);
        store_slot(slotS, Mslot, 4*wv, acc, Mrow, m, q);
    }
    __syncthreads();   // the only cross-wave handoff: root reads slots 0 and 4

    // ---- phase 4: root (wave 0)
    if (wv == 0) {
        const Op op = ops[14];
        int4 bf[8];
        load_bfrag(wbJ, op.w, lane, bf);
        float p[16], Mrow;
        slot_prod(slotS, Mslot, 0, 4, m, q, p, Mrow);
        f32x4 acc[4];
        mfma8(p, bf, acc);
        if (MODE == 0) {
            const int rowOff = s * 2048;
            #pragma unroll
            for (int jt = 0; jt < 4; ++jt)
                #pragma unroll
                for (int r = 0; r < 4; ++r)
                    outAcc[(size_t)(rowOff + b0 + q*4 + r) * 64 + jt*16 + m] =
                        (unsigned short)bfr(acc[jt][r]);
            if (q == 0) outM[rowOff + b0 + m] = Mrow;
        } else {
            float mr[4];
            #pragma unroll
            for (int r = 0; r < 4; ++r) mr[r] = __shfl(Mrow, q * 4 + r, 64);
            #pragma unroll
            for (int jt = 0; jt < 4; ++jt)
                #pragma unroll
                for (int r = 0; r < 4; ++r)
                    outLog[(b0 + q*4 + r) * 64 + jt*16 + m] =
                        (__builtin_amdgcn_logf(acc[jt][r]) + mr[r]) * LN2_F;
        }
    }
}

// ---------------------------------------------------------------------------
// d_in order: 0:x 1:mu 2:log_sigma 3:in_scope_idx, then fold_idx{l}, w{l}
// ---------------------------------------------------------------------------
extern "C" void kernel_launch(void* const* d_in, const int* in_sizes, int n_in,
                              void* d_out, int out_size, void* d_ws, size_t ws_size,
                              hipStream_t stream) {
    const float* x     = (const float*)d_in[0];
    const float* mu    = (const float*)d_in[1];
    const float* lsg   = (const float*)d_in[2];
    const int*   scope = (const int*)d_in[3];
    const int*   f1 = (const int*)d_in[4];   const float* w1 = (const float*)d_in[5];
    const int*   f2 = (const int*)d_in[6];   const float* w2 = (const float*)d_in[7];
    const int*   f3 = (const int*)d_in[8];   const float* w3 = (const float*)d_in[9];
    const int*   f4 = (const int*)d_in[10];  const float* w4 = (const float*)d_in[11];
    const int*   f5 = (const int*)d_in[12];  const float* w5 = (const float*)d_in[13];
    const int*   f6 = (const int*)d_in[14];  const float* w6 = (const float*)d_in[15];
    const int*   f7 = (const int*)d_in[16];  const float* w7 = (const float*)d_in[17];
    const int*   f8 = (const int*)d_in[18];  const float* w8 = (const float*)d_in[19];

    char* ws = (char*)d_ws;
    const unsigned short* wbJ = (const unsigned short*)(ws + WS_WBJ);
    const float* Ag  = (const float*)(ws + WS_A);
    const float* Bg  = (const float*)(ws + WS_B);
    const float* Cg  = (const float*)(ws + WS_C);
    const float* xT  = (const float*)(ws + WS_XT);
    const Op*    sch = (const Op*)(ws + WS_SCHED);
    unsigned short* L4A = (unsigned short*)(ws + WS_L4A);
    float*          L4M = (float*)(ws + WS_L4M);

    prep_kernel<<<576, 256, 0, stream>>>(w1, w2, w3, w4, w5, w6, w7, w8,
                                         mu, lsg, x, scope,
                                         f1, f2, f3, f4, f5, f6, f7, f8, ws);

    // levels 1..4: 16 roots x 128 tiles, 2-wave cooperative trees, pair-ILP
    circuit_coop<0><<<2048, 128, 0, stream>>>(
        wbJ, sch, 16,
        xT, Ag, Bg, Cg,
        nullptr, nullptr,
        L4A, L4M, nullptr);

    // levels 5..8: one tree per batch tile, final natural-log output
    circuit_coop<1><<<128, 128, 0, stream>>>(
        wbJ, sch + 240, 1,
        nullptr, nullptr, nullptr, nullptr,
        L4A, L4M,
        nullptr, nullptr, (float*)d_out);
}

// Round 11
// 139.545 us; speedup vs baseline: 2.2586x; 1.0444x over previous
//
#include <hip/hip_runtime.h>
#include <math.h>

#define LOG2PI_F  0.9189385332046727f
#define INV_LN2_F 1.4426950408889634f
#define LN2_F     0.6931471805599453f
#define SROW      72          // slot row stride in shorts (144B, 16B-aligned rows)

typedef short bf16x8 __attribute__((ext_vector_type(8)));
typedef float f32x4  __attribute__((ext_vector_type(4)));

struct __align__(16) Op { int w; int c0; int c1; int pad; };

// ---- workspace byte offsets -------------------------------------------------
#define WS_WBJ   0u          // bf16[255][8 frag][64 lane][8] pre-swizzled weights
#define WS_A     2097152u    // float[256*64]  leaf coeff A (log2 domain)
#define WS_B     2162688u    // float[256*64]  leaf coeff B
#define WS_C     2228224u    // float[256*64]  leaf coeff C
#define WS_XT    2293760u    // float[256*2048] x gathered+transposed: xT[d][b]
#define WS_SCHED 4390912u    // Op[16*15 @0 .. K14 trees, 15 @240 .. tail L5-8]
#define WS_L4A   4395008u    // bf16[16*2048*64] level-4 acc values
#define WS_L4M   8589312u    // float[16*2048]   level-4 row scales (log2)

__device__ __forceinline__ short bfr(float f) {   // f32 -> bf16 RNE
    unsigned int u = __float_as_uint(f);
    u += 0x7fffu + ((u >> 16) & 1u);
    return (short)(u >> 16);
}

struct F8v { float v[8]; };
__device__ __forceinline__ F8v ld8(const float* p) {
    F8v r;
    float4 a = *(const float4*)p;
    float4 b = *(const float4*)(p + 4);
    r.v[0]=a.x; r.v[1]=a.y; r.v[2]=a.z; r.v[3]=a.w;
    r.v[4]=b.x; r.v[5]=b.y; r.v[6]=b.z; r.v[7]=b.w;
    return r;
}

__device__ __forceinline__ void up8(int4 v, float* o) {   // 8 bf16 -> f32
    o[0] = __uint_as_float(((unsigned)v.x) << 16);
    o[1] = __uint_as_float(((unsigned)v.x) & 0xffff0000u);
    o[2] = __uint_as_float(((unsigned)v.y) << 16);
    o[3] = __uint_as_float(((unsigned)v.y) & 0xffff0000u);
    o[4] = __uint_as_float(((unsigned)v.z) << 16);
    o[5] = __uint_as_float(((unsigned)v.z) & 0xffff0000u);
    o[6] = __uint_as_float(((unsigned)v.w) << 16);
    o[7] = __uint_as_float(((unsigned)v.w) & 0xffff0000u);
}

__device__ __forceinline__ float rmax16(const float hv[16]) {
    float m01 = fmaxf(hv[0], hv[1]),  m23 = fmaxf(hv[2], hv[3]);
    float m45 = fmaxf(hv[4], hv[5]),  m67 = fmaxf(hv[6], hv[7]);
    float m89 = fmaxf(hv[8], hv[9]),  mab = fmaxf(hv[10], hv[11]);
    float mcd = fmaxf(hv[12], hv[13]), mef = fmaxf(hv[14], hv[15]);
    float hm = fmaxf(fmaxf(fmaxf(m01, m23), fmaxf(m45, m67)),
                     fmaxf(fmaxf(m89, mab), fmaxf(mcd, mef)));
    hm = fmaxf(hm, __shfl_xor(hm, 16, 64));
    hm = fmaxf(hm, __shfl_xor(hm, 32, 64));
    return hm;
}

__device__ __forceinline__ void pack_p(const float e[16], bf16x8& a0, bf16x8& a1) {
    int4 p0, p1;
    p0.x = __builtin_amdgcn_perm(__float_as_uint(e[1]),  __float_as_uint(e[0]),  0x07060302u);
    p0.y = __builtin_amdgcn_perm(__float_as_uint(e[3]),  __float_as_uint(e[2]),  0x07060302u);
    p0.z = __builtin_amdgcn_perm(__float_as_uint(e[5]),  __float_as_uint(e[4]),  0x07060302u);
    p0.w = __builtin_amdgcn_perm(__float_as_uint(e[7]),  __float_as_uint(e[6]),  0x07060302u);
    p1.x = __builtin_amdgcn_perm(__float_as_uint(e[9]),  __float_as_uint(e[8]),  0x07060302u);
    p1.y = __builtin_amdgcn_perm(__float_as_uint(e[11]), __float_as_uint(e[10]), 0x07060302u);
    p1.z = __builtin_amdgcn_perm(__float_as_uint(e[13]), __float_as_uint(e[12]), 0x07060302u);
    p1.w = __builtin_amdgcn_perm(__float_as_uint(e[15]), __float_as_uint(e[14]), 0x07060302u);
    a0 = *(bf16x8*)&p0;
    a1 = *(bf16x8*)&p1;
}

// ---------------------------------------------------------------------------
// Prep (unchanged from R10): softmax -> frag-swizzled bf16; leaf coeffs;
// x transpose/gather; schedule build (static-slot level-DFS trees).
// ---------------------------------------------------------------------------
__global__ __launch_bounds__(256) void prep_kernel(
    const float* __restrict__ w1, const float* __restrict__ w2,
    const float* __restrict__ w3, const float* __restrict__ w4,
    const float* __restrict__ w5, const float* __restrict__ w6,
    const float* __restrict__ w7, const float* __restrict__ w8,
    const float* __restrict__ mu, const float* __restrict__ ls,
    const float* __restrict__ x,  const int* __restrict__ scope,
    const int* __restrict__ f1, const int* __restrict__ f2,
    const int* __restrict__ f3, const int* __restrict__ f4,
    const int* __restrict__ f5, const int* __restrict__ f6,
    const int* __restrict__ f7, const int* __restrict__ f8,
    char* __restrict__ ws)
{
    const int bx = blockIdx.x, t = threadIdx.x;
    if (bx < 255) {
        __shared__ float smax[64], ssum[64];
        const int g = bx;
        const float* src;
        if (g < 128)      src = w1 + g * 4096;
        else if (g < 192) src = w2 + (g - 128) * 4096;
        else if (g < 224) src = w3 + (g - 192) * 4096;
        else if (g < 240) src = w4 + (g - 224) * 4096;
        else if (g < 248) src = w5 + (g - 240) * 4096;
        else if (g < 252) src = w6 + (g - 248) * 4096;
        else              src = (g < 254) ? (w7 + (g - 252) * 4096) : w8;
        const int lane = t & 63, wv = t >> 6;
        for (int r = 0; r < 16; ++r) {
            int j = wv * 16 + r;
            float v = src[j * 64 + lane];
            float mx = v;
            for (int d = 1; d < 64; d <<= 1) mx = fmaxf(mx, __shfl_xor(mx, d, 64));
            float e = __expf(v - mx);
            float sm = e;
            for (int d = 1; d < 64; d <<= 1) sm += __shfl_xor(sm, d, 64);
            if (lane == 0) { smax[j] = mx; ssum[j] = sm; }
        }
        __syncthreads();
        unsigned short* dst = (unsigned short*)(ws + WS_WBJ) + g * 4096;
        for (int u = 0; u < 16; ++u) {
            int idx = u * 256 + t;
            int j = idx >> 6, k = idx & 63;
            float v = __expf(src[idx] - smax[j]) / ssum[j];
            int f  = ((j >> 4) << 1) | (k >> 5);
            int ln = (((k >> 3) & 3) << 4) | (j & 15);
            dst[(f * 64 + ln) * 8 + (k & 7)] = (unsigned short)bfr(v);
        }
    } else if (bx < 319) {
        const int idx = (bx - 255) * 256 + t;
        float m = mu[idx], l = ls[idx];
        float is2 = __expf(-2.0f * l);
        ((float*)(ws + WS_A))[idx] = -0.5f * is2 * INV_LN2_F;
        ((float*)(ws + WS_B))[idx] = m * is2 * INV_LN2_F;
        ((float*)(ws + WS_C))[idx] = (-0.5f * m * m * is2 - l - LOG2PI_F) * INV_LN2_F;
    } else if (bx < 575) {
        const int bb = bx - 319;
        const int sd = scope[t];
        float* xT = (float*)(ws + WS_XT);
        #pragma unroll
        for (int i = 0; i < 8; ++i) {
            int b = bb * 8 + i;
            xT[t * 2048 + b] = x[b * 256 + sd];
        }
    } else {
        __shared__ int sf[512];
        for (int i = t; i < 256; i += 256) sf[i]        = f1[i];
        for (int i = t; i < 128; i += 256) sf[256 + i]  = f2[i];
        for (int i = t; i <  64; i += 256) sf[384 + i]  = f3[i];
        for (int i = t; i <  32; i += 256) sf[448 + i]  = f4[i];
        for (int i = t; i <  16; i += 256) sf[480 + i]  = f5[i];
        for (int i = t; i <   8; i += 256) sf[496 + i]  = f6[i];
        for (int i = t; i <   4; i += 256) sf[504 + i]  = f7[i];
        for (int i = t; i <   2; i += 256) sf[508 + i]  = f8[i];
        __syncthreads();
        const int* F1 = &sf[0];   const int* F2 = &sf[256];
        const int* F3 = &sf[384]; const int* F4 = &sf[448];
        const int* F5 = &sf[480]; const int* F6 = &sf[496];
        const int* F7 = &sf[504]; const int* F8 = &sf[508];
        Op* base = (Op*)(ws + WS_SCHED);
        if (t < 16) {
            Op* o = base + t * 15;
            int r0 = F4[2*t], r1 = F4[2*t+1];
            int P[4] = { F3[2*r0], F3[2*r0+1], F3[2*r1], F3[2*r1+1] };
            #pragma unroll
            for (int j = 0; j < 4; ++j) {
                int L0 = F2[2*P[j]], L1 = F2[2*P[j]+1];
                o[2*j]   = { L0 * 4096, F1[2*L0], F1[2*L0+1], 0 };
                o[2*j+1] = { L1 * 4096, F1[2*L1], F1[2*L1+1], 0 };
                o[8+j]   = { (128 + P[j]) * 4096, 0, 0, 0 };
            }
            o[12] = { (192 + r0) * 4096, 0, 0, 0 };
            o[13] = { (192 + r1) * 4096, 0, 0, 0 };
            o[14] = { (224 + t)  * 4096, 0, 0, 0 };
        } else if (t == 16) {
            Op* o = base + 240;
            int g[4] = { F7[2*F8[0]], F7[2*F8[0]+1], F7[2*F8[1]], F7[2*F8[1]+1] };
            #pragma unroll
            for (int a = 0; a < 4; ++a) {
                int l0 = F6[2*g[a]], l1 = F6[2*g[a]+1];
                o[2*a]   = { (240 + l0) * 4096, F5[2*l0], F5[2*l0+1], 0 };
                o[2*a+1] = { (240 + l1) * 4096, F5[2*l1], F5[2*l1+1], 0 };
                o[8+a]   = { (248 + g[a]) * 4096, 0, 0, 0 };
            }
            o[12] = { (252 + F8[0]) * 4096, 0, 0, 0 };
            o[13] = { (252 + F8[1]) * 4096, 0, 0, 0 };
            o[14] = { 254 * 4096, 0, 0, 0 };
        }
    }
}

// ---------------------------------------------------------------------------
// Per-op helpers (linear-domain values with per-row pow2 scale M)
// ---------------------------------------------------------------------------
__device__ __forceinline__ void load_bfrag(const unsigned short* __restrict__ wbJ,
                                           int w, int lane, int4 bf[8]) {
    const int4* wp = (const int4*)(wbJ + w);
    #pragma unroll
    for (int f = 0; f < 8; ++f) bf[f] = wp[f * 64 + lane];   // coalesced 1KB/load
}

__device__ __forceinline__ void prod_norm(const float av[16], const float bv[16],
                                          float MA, float MB,
                                          float p[16], float& Mrow) {
    float pv[16];
    #pragma unroll
    for (int i = 0; i < 16; ++i) pv[i] = av[i] * bv[i];
    const float rm = rmax16(pv);
    const int e = (int)((__float_as_uint(rm) >> 23) & 0xFF) - 127;
    #pragma unroll
    for (int i = 0; i < 16; ++i) p[i] = ldexpf(pv[i], -e);   // exact scaling
    Mrow = MA + MB + (float)e;
}

// rowStart = absolute batch row of this lane-group's m=0
__device__ __forceinline__ void gauss_p(const Op& op,
    const float* __restrict__ xT, const float* __restrict__ Ag,
    const float* __restrict__ Bg, const float* __restrict__ Cg,
    int rowStart, int m, int q, float p[16], float& Mrow)
{
    const int d0 = op.c0, d1 = op.c1;
    const float xv0 = xT[d0 * 2048 + rowStart + m];
    const float xv1 = xT[d1 * 2048 + rowStart + m];
    const float x0s = xv0 * xv0, x1s = xv1 * xv1;
    float hv[16];
    #pragma unroll
    for (int kh = 0; kh < 2; ++kh) {
        const int kb = kh * 32 + q * 8;
        F8v A0 = ld8(Ag + d0*64 + kb), B0 = ld8(Bg + d0*64 + kb);
        F8v C0 = ld8(Cg + d0*64 + kb);
        F8v A1 = ld8(Ag + d1*64 + kb), B1 = ld8(Bg + d1*64 + kb);
        F8v C1 = ld8(Cg + d1*64 + kb);
        #pragma unroll
        for (int i = 0; i < 8; ++i) {
            float t0 = fmaf(A0.v[i], x0s, C0.v[i]);
            t0 = fmaf(B0.v[i], xv0, t0);
            float t1 = fmaf(A1.v[i], x1s, C1.v[i]);
            t1 = fmaf(B1.v[i], xv1, t1);
            hv[kh*8+i] = t0 + t1;
        }
    }
    const float hm = rmax16(hv);
    #pragma unroll
    for (int i = 0; i < 16; ++i) p[i] = __builtin_amdgcn_exp2f(hv[i] - hm);
    Mrow = hm;
}

__device__ __forceinline__ void gprod_p(const Op& op,
    const unsigned short* __restrict__ inAcc, const float* __restrict__ inM,
    int rowStart, int m, int q, float p[16], float& Mrow)
{
    const int4* A4 = (const int4*)(inAcc + (size_t)(op.c0 * 2048 + rowStart + m) * 64);
    const int4* B4 = (const int4*)(inAcc + (size_t)(op.c1 * 2048 + rowStart + m) * 64);
    float av[16], bv[16];
    up8(A4[q], av); up8(A4[4+q], av + 8);
    up8(B4[q], bv); up8(B4[4+q], bv + 8);
    prod_norm(av, bv, inM[op.c0 * 2048 + rowStart + m], inM[op.c1 * 2048 + rowStart + m], p, Mrow);
}

// rowBase = 0 or 16 within the 32-row tile
__device__ __forceinline__ void slot_prod(const unsigned short* slotS, const float* Mslot,
                                          int sA, int sB, int rowBase, int m, int q,
                                          float p[16], float& Mrow)
{
    const int4* A4 = (const int4*)(slotS + sA * 32 * SROW + (rowBase + m) * SROW);
    const int4* B4 = (const int4*)(slotS + sB * 32 * SROW + (rowBase + m) * SROW);
    float av[16], bv[16];
    up8(A4[q], av); up8(A4[4+q], av + 8);
    up8(B4[q], bv); up8(B4[4+q], bv + 8);
    prod_norm(av, bv, Mslot[sA * 32 + rowBase + m], Mslot[sB * 32 + rowBase + m], p, Mrow);
}

__device__ __forceinline__ void mfma8(const float p[16], const int4 bf[8], f32x4 acc[4]) {
    bf16x8 a0, a1;
    pack_p(p, a0, a1);
    #pragma unroll
    for (int jt = 0; jt < 4; ++jt) {
        f32x4 z = {0.f, 0.f, 0.f, 0.f};
        z = __builtin_amdgcn_mfma_f32_16x16x32_bf16(a0, *(bf16x8*)&bf[jt*2+0], z, 0, 0, 0);
        z = __builtin_amdgcn_mfma_f32_16x16x32_bf16(a1, *(bf16x8*)&bf[jt*2+1], z, 0, 0, 0);
        acc[jt] = z;
    }
}

__device__ __forceinline__ void store_slot(unsigned short* slotS, float* Mslot,
                                           int sl, int rowBase, const f32x4 acc[4],
                                           float Mrow, int m, int q)
{
    unsigned short* S = slotS + sl * 32 * SROW;
    #pragma unroll
    for (int jt = 0; jt < 4; ++jt)
        #pragma unroll
        for (int r = 0; r < 4; ++r)
            S[(rowBase + q*4 + r) * SROW + jt*16 + m] = (unsigned short)bfr(acc[jt][r]);
    if (q == 0) Mslot[sl * 32 + rowBase + m] = Mrow;
}

__device__ __forceinline__ void wave_fence() {
    __builtin_amdgcn_wave_barrier();
    __builtin_amdgcn_s_waitcnt(0xC07F);   // lgkmcnt(0)
    __builtin_amdgcn_wave_barrier();
}

// ---------------------------------------------------------------------------
// 4-wave cooperative tree kernel, 32-row tiles. Each op loads its weight
// fragments ONCE and runs both 16-row halves through them (ILP pair) —
// weight L1 traffic per unit work halved vs R10.
//   wave w: leaves -> slots 2w,2w+1 ; L2 mix w reads 2w,2w+1 -> 2w (wave-local)
//   L3 u (waves 0,2): reads 4u,4u+2 -> 4u (cross-wave, syncthreads)
//   root (wave 0): reads 0,4 (syncthreads)
// MODE 0: K14 (Gauss leaves, root -> L4 acc+M). MODE 1: tail L5-8 -> d_out.
// ---------------------------------------------------------------------------
template<int MODE>
__global__ __launch_bounds__(256, 4) void circuit_coop(
    const unsigned short* __restrict__ wbJ,
    const Op* __restrict__ schedG, int ntile,
    const float* __restrict__ xT, const float* __restrict__ Ag,
    const float* __restrict__ Bg, const float* __restrict__ Cg,
    const unsigned short* __restrict__ inAcc, const float* __restrict__ inM,
    unsigned short* __restrict__ outAcc, float* __restrict__ outM,
    float* __restrict__ outLog)
{
    __shared__ __align__(16) unsigned short slotS[8 * 32 * SROW];  // 36.9 KB
    __shared__ float Mslot[8 * 32];
    __shared__ Op ops[16];

    const int t    = threadIdx.x;
    const int wv   = t >> 6;
    const int lane = t & 63;
    const int m    = lane & 15;
    const int q    = lane >> 4;
    const int s    = blockIdx.x / ntile;          // s-major: L2 weight locality
    const int b0   = (blockIdx.x % ntile) * 32;

    if (t < 15) *(int4*)&ops[t] = ((const int4*)(schedG + s * 15))[t];
    __syncthreads();

    // ---- phase 1: 2 leaves per wave; each leaf runs both halves on one B-load
    #pragma unroll
    for (int i = 0; i < 2; ++i) {
        const int sl = 2 * wv + i;
        const Op op = ops[sl];
        int4 bf[8];
        load_bfrag(wbJ, op.w, lane, bf);
        float p0[16], p1[16], M0, M1;
        if (MODE == 0) {
            gauss_p(op, xT, Ag, Bg, Cg, b0,      m, q, p0, M0);
            gauss_p(op, xT, Ag, Bg, Cg, b0 + 16, m, q, p1, M1);
        } else {
            gprod_p(op, inAcc, inM, b0,      m, q, p0, M0);
            gprod_p(op, inAcc, inM, b0 + 16, m, q, p1, M1);
        }
        f32x4 acc0[4], acc1[4];
        mfma8(p0, bf, acc0);
        mfma8(p1, bf, acc1);
        store_slot(slotS, Mslot, sl, 0,  acc0, M0, m, q);
        store_slot(slotS, Mslot, sl, 16, acc1, M1, m, q);
    }
    wave_fence();

    // ---- phase 2: L2 mix j = wv, reads own slots 2j,2j+1 -> 2j (both halves)
    {
        const Op op = ops[8 + wv];
        int4 bf[8];
        load_bfrag(wbJ, op.w, lane, bf);
        float p0[16], p1[16], M0, M1;
        slot_prod(slotS, Mslot, 2*wv, 2*wv + 1, 0,  m, q, p0, M0);
        slot_prod(slotS, Mslot, 2*wv, 2*wv + 1, 16, m, q, p1, M1);
        f32x4 acc0[4], acc1[4];
        mfma8(p0, bf, acc0);
        mfma8(p1, bf, acc1);
        store_slot(slotS, Mslot, 2*wv, 0,  acc0, M0, m, q);
        store_slot(slotS, Mslot, 2*wv, 16, acc1, M1, m, q);
    }
    __syncthreads();

    // ---- phase 3: L3 mix u on waves 0,2: reads 4u,4u+2 -> 4u
    if ((wv & 1) == 0) {
        const int u = wv >> 1;
        const Op op = ops[12 + u];
        int4 bf[8];
        load_bfrag(wbJ, op.w, lane, bf);
        float p0[16], p1[16], M0, M1;
        slot_prod(slotS, Mslot, 4*u, 4*u + 2, 0,  m, q, p0, M0);
        slot_prod(slotS, Mslot, 4*u, 4*u + 2, 16, m, q, p1, M1);
        f32x4 acc0[4], acc1[4];
        mfma8(p0, bf, acc0);
        mfma8(p1, bf, acc1);
        store_slot(slotS, Mslot, 4*u, 0,  acc0, M0, m, q);
        store_slot(slotS, Mslot, 4*u, 16, acc1, M1, m, q);
    }
    __syncthreads();

    // ---- phase 4: root (wave 0): reads slots 0,4 (both halves)
    if (wv == 0) {
        const Op op = ops[14];
        int4 bf[8];
        load_bfrag(wbJ, op.w, lane, bf);
        float p0[16], p1[16], M0, M1;
        slot_prod(slotS, Mslot, 0, 4, 0,  m, q, p0, M0);
        slot_prod(slotS, Mslot, 0, 4, 16, m, q, p1, M1);
        f32x4 acc0[4], acc1[4];
        mfma8(p0, bf, acc0);
        mfma8(p1, bf, acc1);
        if (MODE == 0) {
            const int rowOff = s * 2048 + b0;
            #pragma unroll
            for (int jt = 0; jt < 4; ++jt)
                #pragma unroll
                for (int r = 0; r < 4; ++r) {
                    outAcc[(size_t)(rowOff +      q*4 + r) * 64 + jt*16 + m] =
                        (unsigned short)bfr(acc0[jt][r]);
                    outAcc[(size_t)(rowOff + 16 + q*4 + r) * 64 + jt*16 + m] =
                        (unsigned short)bfr(acc1[jt][r]);
                }
            if (q == 0) {
                outM[rowOff + m]      = M0;
                outM[rowOff + 16 + m] = M1;
            }
        } else {
            float mr0[4], mr1[4];
            #pragma unroll
            for (int r = 0; r < 4; ++r) {
                mr0[r] = __shfl(M0, q * 4 + r, 64);
                mr1[r] = __shfl(M1, q * 4 + r, 64);
            }
            #pragma unroll
            for (int jt = 0; jt < 4; ++jt)
                #pragma unroll
                for (int r = 0; r < 4; ++r) {
                    outLog[(b0 +      q*4 + r) * 64 + jt*16 + m] =
                        (__builtin_amdgcn_logf(acc0[jt][r]) + mr0[r]) * LN2_F;
                    outLog[(b0 + 16 + q*4 + r) * 64 + jt*16 + m] =
                        (__builtin_amdgcn_logf(acc1[jt][r]) + mr1[r]) * LN2_F;
                }
        }
    }
}

// ---------------------------------------------------------------------------
// d_in order: 0:x 1:mu 2:log_sigma 3:in_scope_idx, then fold_idx{l}, w{l}
// ---------------------------------------------------------------------------
extern "C" void kernel_launch(void* const* d_in, const int* in_sizes, int n_in,
                              void* d_out, int out_size, void* d_ws, size_t ws_size,
                              hipStream_t stream) {
    const float* x     = (const float*)d_in[0];
    const float* mu    = (const float*)d_in[1];
    const float* lsg   = (const float*)d_in[2];
    const int*   scope = (const int*)d_in[3];
    const int*   f1 = (const int*)d_in[4];   const float* w1 = (const float*)d_in[5];
    const int*   f2 = (const int*)d_in[6];   const float* w2 = (const float*)d_in[7];
    const int*   f3 = (const int*)d_in[8];   const float* w3 = (const float*)d_in[9];
    const int*   f4 = (const int*)d_in[10];  const float* w4 = (const float*)d_in[11];
    const int*   f5 = (const int*)d_in[12];  const float* w5 = (const float*)d_in[13];
    const int*   f6 = (const int*)d_in[14];  const float* w6 = (const float*)d_in[15];
    const int*   f7 = (const int*)d_in[16];  const float* w7 = (const float*)d_in[17];
    const int*   f8 = (const int*)d_in[18];  const float* w8 = (const float*)d_in[19];

    char* ws = (char*)d_ws;
    const unsigned short* wbJ = (const unsigned short*)(ws + WS_WBJ);
    const float* Ag  = (const float*)(ws + WS_A);
    const float* Bg  = (const float*)(ws + WS_B);
    const float* Cg  = (const float*)(ws + WS_C);
    const float* xT  = (const float*)(ws + WS_XT);
    const Op*    sch = (const Op*)(ws + WS_SCHED);
    unsigned short* L4A = (unsigned short*)(ws + WS_L4A);
    float*          L4M = (float*)(ws + WS_L4M);

    prep_kernel<<<576, 256, 0, stream>>>(w1, w2, w3, w4, w5, w6, w7, w8,
                                         mu, lsg, x, scope,
                                         f1, f2, f3, f4, f5, f6, f7, f8, ws);

    // levels 1..4: 16 roots x 64 tiles of 32 rows, 4-wave cooperative trees
    circuit_coop<0><<<1024, 256, 0, stream>>>(
        wbJ, sch, 64,
        xT, Ag, Bg, Cg,
        nullptr, nullptr,
        L4A, L4M, nullptr);

    // levels 5..8: 64 tiles of 32 rows, final natural-log output
    circuit_coop<1><<<64, 256, 0, stream>>>(
        wbJ, sch + 240, 64,
        nullptr, nullptr, nullptr, nullptr,
        L4A, L4M,
        nullptr, nullptr, (float*)d_out);
}